// Round 15
// baseline (4150.903 us; speedup 1.0000x reference)
//
#include <hip/hip_runtime.h>
#include <math.h>

#define BATCH 16
#define SEQ 512
#define DIM 2048
#define HID 1024
#define NPAIRS 128
#define TLEN 384
#define NUN 256

typedef unsigned long long ull;
typedef short bf16x8 __attribute__((ext_vector_type(8)));
typedef float f32x4 __attribute__((ext_vector_type(4)));
typedef double f64x4 __attribute__((ext_vector_type(4)));

__device__ __forceinline__ unsigned short f2bf(float f) {
  unsigned u = __float_as_uint(f);
  unsigned r = (u + 0x7FFFu + ((u >> 16) & 1u)) >> 16;   // RNE
  return (unsigned short)r;
}
__device__ __forceinline__ unsigned ccord(float v) {
  unsigned u = __float_as_uint(v);
  return (u & 0x80000000u) ? ~u : (u | 0x80000000u);
}

// ---------------------------------------------------------------------------
// Probe: determine the v_mfma_f64_16x16x4 D-register layout at runtime.
// (verified working on this HW in round 14 — probe selected a valid H and
// the full pipeline passed bit-exact)
// ---------------------------------------------------------------------------
__global__ __launch_bounds__(64)
void cc_probe_f64(int* __restrict__ flag) {
  __shared__ double Af[16][4];
  __shared__ double Bf[4][16];
  int l = threadIdx.x;
  if (l < 16)
#pragma unroll
    for (int k = 0; k < 4; ++k) {
      Af[l][k] = 1.0 + (double)l + 16.0 * k;
      Bf[k][l] = 2.0 + 3.0 * (double)l + 5.0 * k;
    }
  __syncthreads();
  int lr = l & 15, lk = l >> 4;
  double a = Af[lr][lk];
  double b = Bf[lk][lr];
  f64x4 d = {0.0, 0.0, 0.0, 0.0};
  d = __builtin_amdgcn_mfma_f64_16x16x4f64(a, b, d, 0, 0, 0);
  int best = 255;
  for (int H = 0; H < 4; ++H) {
    bool ok = true;
#pragma unroll
    for (int v = 0; v < 4; ++v) {
      int r, c;
      if (H == 0)      { r = 4 * lk + v; c = lr; }
      else if (H == 1) { r = lr; c = 4 * lk + v; }
      else if (H == 2) { r = lk + 4 * v; c = lr; }
      else             { r = lr; c = lk + 4 * v; }
      double tr = 0.0;
#pragma unroll
      for (int k = 0; k < 4; ++k) tr += Af[r][k] * Bf[k][c];
      if (d[v] != tr) ok = false;
    }
    ull m = __ballot(ok);
    if (m == ~0ull) { best = H; break; }
  }
  if (l == 0) *flag = best;
}

// ---------------------------------------------------------------------------
// GEMM 1: h = gelu(x @ imp_w1 + b1). f64 MFMA, tile 128x64, BK=16, 4 waves
// (each wave 64x32 = 8 MFMA per k4 from 6 LDS reads). VALU fallback matched
// to the new geometry (dead code unless probe fails). f32 store points kept.
// ---------------------------------------------------------------------------
__global__ __launch_bounds__(256)
void cc_gemm_h(const float* __restrict__ A, const float* __restrict__ Bw,
               const float* __restrict__ bias, float* __restrict__ C,
               const int* __restrict__ flagp) {
  const int N = HID, K = DIM;
  __shared__ double As[16][130];   // [k][m], 128 rows
  __shared__ double Bs[16][66];    // [k][n], 64 cols
  const int H = *flagp;
  int tid = threadIdx.x;
  int lane = tid & 63, wave = tid >> 6;
  int wr = wave >> 1, wc = wave & 1;
  int lr = lane & 15, lk = lane >> 4;
  int pr[4], pc[4];
#pragma unroll
  for (int v = 0; v < 4; ++v) {
    if (H == 0)      { pr[v] = 4 * lk + v; pc[v] = lr; }
    else if (H == 1) { pr[v] = lr; pc[v] = 4 * lk + v; }
    else if (H == 2) { pr[v] = lk + 4 * v; pc[v] = lr; }
    else             { pr[v] = lr; pc[v] = lk + 4 * v; }
  }
  int tx = tid % 16, ty = tid / 16;
  int m0 = blockIdx.y * 128, n0 = blockIdx.x * 64;
  f64x4 acc[4][2] = {};
  double vacc[8][4] = {};
  for (int k0 = 0; k0 < K; k0 += 16) {
#pragma unroll
    for (int u = 0; u < 8; ++u) {
      int l = tid + u * 256;
      int r = l >> 4, k = l & 15;
      As[k][r] = (double)A[(size_t)(m0 + r) * K + k0 + k];
    }
#pragma unroll
    for (int u = 0; u < 4; ++u) {
      int l = tid + u * 256;
      int kb = l >> 6, n = l & 63;
      Bs[kb][n] = (double)Bw[(size_t)(k0 + kb) * N + n0 + n];
    }
    __syncthreads();
    if (H < 4) {
#pragma unroll
      for (int k4 = 0; k4 < 4; ++k4) {
        int kk = k4 * 4 + lk;
        double a0 = As[kk][wr * 64 + lr];
        double a1 = As[kk][wr * 64 + 16 + lr];
        double a2 = As[kk][wr * 64 + 32 + lr];
        double a3 = As[kk][wr * 64 + 48 + lr];
        double b0 = Bs[kk][wc * 32 + lr];
        double b1 = Bs[kk][wc * 32 + 16 + lr];
        acc[0][0] = __builtin_amdgcn_mfma_f64_16x16x4f64(a0, b0, acc[0][0], 0, 0, 0);
        acc[0][1] = __builtin_amdgcn_mfma_f64_16x16x4f64(a0, b1, acc[0][1], 0, 0, 0);
        acc[1][0] = __builtin_amdgcn_mfma_f64_16x16x4f64(a1, b0, acc[1][0], 0, 0, 0);
        acc[1][1] = __builtin_amdgcn_mfma_f64_16x16x4f64(a1, b1, acc[1][1], 0, 0, 0);
        acc[2][0] = __builtin_amdgcn_mfma_f64_16x16x4f64(a2, b0, acc[2][0], 0, 0, 0);
        acc[2][1] = __builtin_amdgcn_mfma_f64_16x16x4f64(a2, b1, acc[2][1], 0, 0, 0);
        acc[3][0] = __builtin_amdgcn_mfma_f64_16x16x4f64(a3, b0, acc[3][0], 0, 0, 0);
        acc[3][1] = __builtin_amdgcn_mfma_f64_16x16x4f64(a3, b1, acc[3][1], 0, 0, 0);
      }
    } else {
#pragma unroll
      for (int k = 0; k < 16; ++k) {
        double aa[8], bb[4];
#pragma unroll
        for (int fi = 0; fi < 8; ++fi) aa[fi] = As[k][ty * 8 + fi];
#pragma unroll
        for (int fj = 0; fj < 4; ++fj) bb[fj] = Bs[k][tx * 4 + fj];
#pragma unroll
        for (int fi = 0; fi < 8; ++fi)
#pragma unroll
          for (int fj = 0; fj < 4; ++fj)
            vacc[fi][fj] = fma(aa[fi], bb[fj], vacc[fi][fj]);
      }
    }
    __syncthreads();
  }
  if (H < 4) {
#pragma unroll
    for (int fi = 0; fi < 4; ++fi)
#pragma unroll
      for (int fj = 0; fj < 2; ++fj)
#pragma unroll
        for (int v = 0; v < 4; ++v) {
          int m = m0 + wr * 64 + fi * 16 + pr[v];
          int n = n0 + wc * 32 + fj * 16 + pc[v];
          float pre = (float)(acc[fi][fj][v] + (double)bias[n]);  // f32 store
          double vv = (double)pre;
          double g = 0.5 * vv * (1.0 + erf(vv * 0.70710678118654752440));
          C[(size_t)m * N + n] = (float)g;                        // f32 store
        }
  } else {
#pragma unroll
    for (int fi = 0; fi < 8; ++fi)
#pragma unroll
      for (int fj = 0; fj < 4; ++fj) {
        int m = m0 + ty * 8 + fi, n = n0 + tx * 4 + fj;
        float pre = (float)(vacc[fi][fj] + (double)bias[n]);
        double vv = (double)pre;
        double g = 0.5 * vv * (1.0 + erf(vv * 0.70710678118654752440));
        C[(size_t)m * N + n] = (float)g;
      }
  }
}

// ---------------------------------------------------------------------------
// imp = sigmoid(h @ imp_w2 + b2); logit rounded to f32, imp stored f32
// ---------------------------------------------------------------------------
__global__ __launch_bounds__(256)
void cc_imp2(const float* __restrict__ h, const float* __restrict__ w2,
             const float* __restrict__ b2, float* __restrict__ imp) {
  int row = blockIdx.x, tid = threadIdx.x;
  __shared__ double red[256];
  double s = 0.0;
  const float* hr = h + (size_t)row * HID;
  for (int k = tid; k < HID; k += 256) s = fma((double)hr[k], (double)w2[k], s);
  red[tid] = s;
  __syncthreads();
  for (int off = 128; off > 0; off >>= 1) {
    if (tid < off) red[tid] += red[tid + off];
    __syncthreads();
  }
  if (tid == 0) {
    float logit = (float)(red[0] + (double)b2[0]);          // f32 store point
    double sg = 1.0 / (1.0 + exp(-(double)logit));
    imp[row] = (float)sg;                                   // f32 store point
  }
}

// ---------------------------------------------------------------------------
// per-batch min-max normalize in f32, then w = max(norm, 0.1f)
// ---------------------------------------------------------------------------
__global__ __launch_bounds__(512)
void cc_minmax(const float* __restrict__ imp, float* __restrict__ w) {
  int b = blockIdx.x, tid = threadIdx.x;
  __shared__ float mn[512], mx[512];
  float v = imp[b * SEQ + tid];
  mn[tid] = v; mx[tid] = v;
  __syncthreads();
  for (int off = 256; off > 0; off >>= 1) {
    if (tid < off) {
      mn[tid] = fminf(mn[tid], mn[tid + off]);
      mx[tid] = fmaxf(mx[tid], mx[tid + off]);
    }
    __syncthreads();
  }
  float lo = mn[0], hi = mx[0];
  float nv = (hi > lo) ? (v - lo) / (hi - lo) : v;
  w[b * SEQ + tid] = fmaxf(nv, 0.1f);
}

// ---------------------------------------------------------------------------
// row L2 norms of x: exact f64 sumsq, sqrt, rounded to f32, clamp 1e-12f
// ---------------------------------------------------------------------------
__global__ __launch_bounds__(256)
void cc_rownorm(const float* __restrict__ x, float* __restrict__ rn) {
  int row = blockIdx.x, tid = threadIdx.x;
  __shared__ double red[256];
  double s = 0.0;
  const float* xr = x + (size_t)row * DIM;
  for (int k = tid; k < DIM; k += 256) {
    double v = xr[k];
    s = fma(v, v, s);
  }
  red[tid] = s;
  __syncthreads();
  for (int off = 128; off > 0; off >>= 1) {
    if (tid < off) red[tid] += red[tid + off];
    __syncthreads();
  }
  if (tid == 0) rn[row] = fmaxf((float)sqrt(red[0]), 1e-12f);
}

// ---------------------------------------------------------------------------
// score[b,s,t]: byte-identical to round-14 passing kernel (f64 MFMA 64x64
// BK=16 + VALU fallback; f32 store points).
// ---------------------------------------------------------------------------
__global__ __launch_bounds__(256)
void cc_gemm_score(const float* __restrict__ X, const float* __restrict__ rn,
                   const float* __restrict__ w, float* __restrict__ score,
                   const int* __restrict__ flagp) {
  const int b = blockIdx.z;
  __shared__ double As[16][66];
  __shared__ double Bs[16][66];
  const int H = *flagp;
  int tid = threadIdx.x;
  int lane = tid & 63, wave = tid >> 6;
  int wr = wave >> 1, wc = wave & 1;
  int lr = lane & 15, lk = lane >> 4;
  int pr[4], pc[4];
#pragma unroll
  for (int v = 0; v < 4; ++v) {
    if (H == 0)      { pr[v] = 4 * lk + v; pc[v] = lr; }
    else if (H == 1) { pr[v] = lr; pc[v] = 4 * lk + v; }
    else if (H == 2) { pr[v] = lk + 4 * v; pc[v] = lr; }
    else             { pr[v] = lr; pc[v] = lk + 4 * v; }
  }
  int tx = tid % 16, ty = tid / 16;
  int s0 = blockIdx.y * 64, t0 = blockIdx.x * 64;
  const float* Xb = X + (size_t)b * SEQ * DIM;
  const float* rnb = rn + b * SEQ;
  f64x4 acc[2][2] = {{{0.,0.,0.,0.},{0.,0.,0.,0.}},{{0.,0.,0.,0.},{0.,0.,0.,0.}}};
  double vacc[4][4] = {};
  for (int k0 = 0; k0 < DIM; k0 += 16) {
#pragma unroll
    for (int u = 0; u < 4; ++u) {
      int l = tid + u * 256;
      int r = l >> 4, k = l & 15;
      As[k][r] = (double)(Xb[(size_t)(s0 + r) * DIM + k0 + k] / rnb[s0 + r]);
      Bs[k][r] = (double)(Xb[(size_t)(t0 + r) * DIM + k0 + k] / rnb[t0 + r]);
    }
    __syncthreads();
    if (H < 4) {
#pragma unroll
      for (int k4 = 0; k4 < 4; ++k4) {
        int kk = k4 * 4 + lk;
        double a0 = As[kk][wr * 32 + lr];
        double a1 = As[kk][wr * 32 + 16 + lr];
        double b0 = Bs[kk][wc * 32 + lr];
        double b1 = Bs[kk][wc * 32 + 16 + lr];
        acc[0][0] = __builtin_amdgcn_mfma_f64_16x16x4f64(a0, b0, acc[0][0], 0, 0, 0);
        acc[0][1] = __builtin_amdgcn_mfma_f64_16x16x4f64(a0, b1, acc[0][1], 0, 0, 0);
        acc[1][0] = __builtin_amdgcn_mfma_f64_16x16x4f64(a1, b0, acc[1][0], 0, 0, 0);
        acc[1][1] = __builtin_amdgcn_mfma_f64_16x16x4f64(a1, b1, acc[1][1], 0, 0, 0);
      }
    } else {
#pragma unroll
      for (int k = 0; k < 16; ++k) {
        double a0 = As[k][ty * 4 + 0], a1 = As[k][ty * 4 + 1];
        double a2 = As[k][ty * 4 + 2], a3 = As[k][ty * 4 + 3];
        double b0 = Bs[k][tx * 4 + 0], b1 = Bs[k][tx * 4 + 1];
        double b2 = Bs[k][tx * 4 + 2], b3 = Bs[k][tx * 4 + 3];
        vacc[0][0] = fma(a0, b0, vacc[0][0]); vacc[0][1] = fma(a0, b1, vacc[0][1]);
        vacc[0][2] = fma(a0, b2, vacc[0][2]); vacc[0][3] = fma(a0, b3, vacc[0][3]);
        vacc[1][0] = fma(a1, b0, vacc[1][0]); vacc[1][1] = fma(a1, b1, vacc[1][1]);
        vacc[1][2] = fma(a1, b2, vacc[1][2]); vacc[1][3] = fma(a1, b3, vacc[1][3]);
        vacc[2][0] = fma(a2, b0, vacc[2][0]); vacc[2][1] = fma(a2, b1, vacc[2][1]);
        vacc[2][2] = fma(a2, b2, vacc[2][2]); vacc[2][3] = fma(a2, b3, vacc[2][3]);
        vacc[3][0] = fma(a3, b0, vacc[3][0]); vacc[3][1] = fma(a3, b1, vacc[3][1]);
        vacc[3][2] = fma(a3, b2, vacc[3][2]); vacc[3][3] = fma(a3, b3, vacc[3][3]);
      }
    }
    __syncthreads();
  }
  if (H < 4) {
#pragma unroll
    for (int i = 0; i < 2; ++i)
#pragma unroll
      for (int j = 0; j < 2; ++j)
#pragma unroll
        for (int v = 0; v < 4; ++v) {
          int s = s0 + wr * 32 + i * 16 + pr[v];
          int t = t0 + wc * 32 + j * 16 + pc[v];
          float vv;
          if (s == t) vv = -1.0f;
          else {
            float sim = (float)acc[i][j][v];                  // f32 store
            float wp = w[b * SEQ + s] * w[b * SEQ + t];       // f32 mul
            vv = sim / wp;                                    // f32 div
          }
          score[((size_t)b * SEQ + s) * SEQ + t] = vv;
        }
  } else {
#pragma unroll
    for (int i = 0; i < 4; ++i)
#pragma unroll
      for (int j = 0; j < 4; ++j) {
        int s = s0 + ty * 4 + i, t = t0 + tx * 4 + j;
        float vv;
        if (s == t) vv = -1.0f;
        else {
          float sim = (float)vacc[i][j];
          float wp = w[b * SEQ + s] * w[b * SEQ + t];
          vv = sim / wp;
        }
        score[((size_t)b * SEQ + s) * SEQ + t] = vv;
      }
  }
}

// ---------------------------------------------------------------------------
// Greedy: ONE WAVE per batch, round-7 structure, but wave reductions use a
// u32 chain (6 single-bpermute shfls on the ordered value) + ballot + one
// extraction shfl — half the ds_bpermute latency of the u64 chains.
// Tie-breaks identical: within-lane u64 compare picks smallest row/col; lane
// index order == row/col order, so lowest ballot lane == smallest index.
// ---------------------------------------------------------------------------
__global__ __launch_bounds__(64)
void cc_greedy(const float* __restrict__ score, int* __restrict__ pi,
               int* __restrict__ pj, unsigned char* __restrict__ availg) {
  const int b = blockIdx.x;
  const float* S = score + (size_t)b * SEQ * SEQ;
  const int lane = threadIdx.x;
  __shared__ uint2 availv[SEQ / 8];
  unsigned char* avail = (unsigned char*)availv;
  __shared__ int rargL[SEQ];
  __shared__ int spi[NPAIRS], spj[NPAIRS];
  unsigned rhi8[8];
  int rarg8[8];
  unsigned am = 0xFFu;

  availv[lane] = make_uint2(0x01010101u, 0x01010101u);

  // ---- init: 8 independent row scans per lane ----
  {
    float bv[8]; int bc[8];
#pragma unroll
    for (int q = 0; q < 8; ++q) { bv[q] = -INFINITY; bc[q] = 0; }
    for (int c4 = 0; c4 < SEQ / 4; ++c4) {
#pragma unroll
      for (int q = 0; q < 8; ++q) {
        int r = lane * 8 + q;
        float4 v = ((const float4*)(S + (size_t)r * SEQ))[c4];
        int cc = c4 * 4;
        if (v.x > bv[q]) { bv[q] = v.x; bc[q] = cc; }
        if (v.y > bv[q]) { bv[q] = v.y; bc[q] = cc + 1; }
        if (v.z > bv[q]) { bv[q] = v.z; bc[q] = cc + 2; }
        if (v.w > bv[q]) { bv[q] = v.w; bc[q] = cc + 3; }
      }
    }
#pragma unroll
    for (int q = 0; q < 8; ++q) {
      rhi8[q] = ccord(bv[q]);
      rarg8[q] = bc[q];
      rargL[lane * 8 + q] = bc[q];
    }
  }
  __syncthreads();

  for (int t = 0; t < NPAIRS; ++t) {
    // ---- pick: per-lane best (u64, register-only), wave-reduce u32 ----
    ull key = 0ULL;
#pragma unroll
    for (int q = 0; q < 8; ++q) {
      if (am & (1u << q)) {
        ull k = ((ull)rhi8[q] << 32) | (unsigned)((SEQ - 1) - (lane * 8 + q));
        if (k > key) key = k;
      }
    }
    unsigned myhi = (unsigned)(key >> 32);
    int myrow = (SEQ - 1) - (int)(key & 0xFFFFFFFFull);
    unsigned mx = myhi;
#pragma unroll
    for (int off = 1; off < 64; off <<= 1) {
      unsigned o = __shfl_xor(mx, off, 64);
      if (o > mx) mx = o;
    }
    ull pm = __ballot(myhi == mx);
    int sl = __ffsll(pm) - 1;
    const int i = __shfl(myrow, sl, 64);
    const int j = rargL[i];
    if (lane == 0) {
      spi[t] = i; spj[t] = j;
      avail[i] = 0; avail[j] = 0;
    }
    if ((i >> 3) == lane) am &= ~(1u << (i & 7));
    if ((j >> 3) == lane) am &= ~(1u << (j & 7));
    __syncthreads();

    // ---- refresh rows whose cached argmax column just died ----
    unsigned needmask = 0u;
#pragma unroll
    for (int q = 0; q < 8; ++q)
      if ((am & (1u << q)) && (rarg8[q] == i || rarg8[q] == j))
        needmask |= (1u << q);
    for (int q = 0; q < 8; ++q) {
      ull m = __ballot((needmask >> q) & 1u);
      while (m) {
        int src = __ffsll(m) - 1;
        m &= m - 1;
        int r = src * 8 + q;
        const float4* row4 = (const float4*)(S + (size_t)r * SEQ) + lane * 2;
        float4 v0 = row4[0], v1 = row4[1];
        uint2 av = availv[lane];
        float nv = -INFINITY; int nc = -1;
        if ((av.x & 0x000000FFu) && v0.x > nv) { nv = v0.x; nc = 0; }
        if ((av.x & 0x0000FF00u) && v0.y > nv) { nv = v0.y; nc = 1; }
        if ((av.x & 0x00FF0000u) && v0.z > nv) { nv = v0.z; nc = 2; }
        if ((av.x & 0xFF000000u) && v0.w > nv) { nv = v0.w; nc = 3; }
        if ((av.y & 0x000000FFu) && v1.x > nv) { nv = v1.x; nc = 4; }
        if ((av.y & 0x0000FF00u) && v1.y > nv) { nv = v1.y; nc = 5; }
        if ((av.y & 0x00FF0000u) && v1.z > nv) { nv = v1.z; nc = 6; }
        if ((av.y & 0xFF000000u) && v1.w > nv) { nv = v1.w; nc = 7; }
        unsigned rhi2 = (nc >= 0) ? ccord(nv) : 0u;
        unsigned mx2 = rhi2;
#pragma unroll
        for (int off = 1; off < 64; off <<= 1) {
          unsigned o = __shfl_xor(mx2, off, 64);
          if (o > mx2) mx2 = o;
        }
        ull pm2 = __ballot(rhi2 == mx2);
        int sl2 = __ffsll(pm2) - 1;
        int gcol = __shfl(lane * 8 + nc, sl2, 64);
        if (lane == src) {
          rhi8[q] = mx2;
          rarg8[q] = gcol;
          rargL[r] = gcol;
        }
      }
    }
    __syncthreads();
  }

  for (int t2 = lane; t2 < NPAIRS; t2 += 64) {
    pi[b * NPAIRS + t2] = spi[t2];
    pj[b * NPAIRS + t2] = spj[t2];
  }
#pragma unroll
  for (int q = 0; q < 8; ++q) {
    int r = lane * 8 + q;
    availg[b * SEQ + r] = avail[r];
  }
}

// ---------------------------------------------------------------------------
// unmerged index list via prefix sum (ascending order)
// ---------------------------------------------------------------------------
__global__ __launch_bounds__(512)
void cc_unmerged(const unsigned char* __restrict__ availg, int* __restrict__ un) {
  int b = blockIdx.x, tid = threadIdx.x;
  __shared__ int ps[SEQ];
  int flag = availg[b * SEQ + tid];
  ps[tid] = flag;
  __syncthreads();
  for (int off = 1; off < SEQ; off <<= 1) {
    int v = (tid >= off) ? ps[tid - off] : 0;
    __syncthreads();
    ps[tid] += v;
    __syncthreads();
  }
  int pos = ps[tid] - flag;
  if (flag && pos < NUN) un[b * NUN + pos] = tid;
}

// ---------------------------------------------------------------------------
// copy unmerged tokens to out rows [128, 384)
// ---------------------------------------------------------------------------
__global__ __launch_bounds__(256)
void cc_unmerged_copy(const float* __restrict__ x, const int* __restrict__ un,
                      float* __restrict__ out) {
  int idx = blockIdx.x;
  int b = idx / NUN, u_ = idx % NUN;
  int s = un[idx];
  const float4* src = (const float4*)(x + ((size_t)b * SEQ + s) * DIM);
  float4* dst = (float4*)(out + ((size_t)b * TLEN + NPAIRS + u_) * DIM);
  for (int u = threadIdx.x; u < DIM / 4; u += 256) dst[u] = src[u];
}

// ---------------------------------------------------------------------------
// W [K][N] f32 row-major -> Wt [N][K] bf16. 32x32 tiles via LDS.
// ---------------------------------------------------------------------------
__global__ __launch_bounds__(256)
void cc_transpose_bf16(const float* __restrict__ W, unsigned short* __restrict__ Wt,
                       int K, int N) {
  __shared__ float t[32][33];
  int tx = threadIdx.x & 31, ty = threadIdx.x >> 5;
  int k0 = blockIdx.y * 32, n0 = blockIdx.x * 32;
#pragma unroll
  for (int u = 0; u < 4; ++u) {
    int kk = ty + u * 8;
    t[kk][tx] = W[(size_t)(k0 + kk) * N + n0 + tx];
  }
  __syncthreads();
#pragma unroll
  for (int u = 0; u < 4; ++u) {
    int nn = ty + u * 8;
    Wt[(size_t)(n0 + nn) * K + k0 + tx] = f2bf(t[tx][nn]);
  }
}

// ---------------------------------------------------------------------------
// m1 = gelu(pair @ mrg_w1 + b1) via bf16 MFMA 16x16x32; OUTPUT bf16 (halves
// m2 staging traffic; well within the 0.101 threshold).
// ---------------------------------------------------------------------------
__global__ __launch_bounds__(256)
void cc_gemm_m1m(const float* __restrict__ x, const int* __restrict__ pi,
                 const int* __restrict__ pj, const unsigned short* __restrict__ Bt,
                 const float* __restrict__ bias, unsigned short* __restrict__ C) {
  __shared__ unsigned short Asm[128][40];
  __shared__ unsigned short Bsm[128][40];
  int tid = threadIdx.x;
  int lane = tid & 63, wave = tid >> 6;
  int wm = wave >> 1, wn = wave & 1;
  int m0 = blockIdx.y * 128, n0 = blockIdx.x * 128;
  int lr = lane & 15, lk = lane >> 4;
  f32x4 acc[4][4] = {};
  const int r = tid >> 1, kh = tid & 1;
  const int mg = m0 + r;
  const int bb = mg >> 7;
  const int ti_ = pi[mg], tj_ = pj[mg];
  for (int k0 = 0; k0 < 2 * DIM; k0 += 32) {
    {
      int kk = k0 + kh * 16;
      int tok = (kk < DIM) ? ti_ : tj_;
      int kc = (kk < DIM) ? kk : kk - DIM;
      const float* src = x + ((size_t)bb * SEQ + tok) * DIM + kc;
      float4 f0 = *(const float4*)(src);
      float4 f1 = *(const float4*)(src + 4);
      float4 f2 = *(const float4*)(src + 8);
      float4 f3 = *(const float4*)(src + 12);
      unsigned short bvals[16];
      bvals[0] = f2bf(f0.x); bvals[1] = f2bf(f0.y); bvals[2] = f2bf(f0.z); bvals[3] = f2bf(f0.w);
      bvals[4] = f2bf(f1.x); bvals[5] = f2bf(f1.y); bvals[6] = f2bf(f1.z); bvals[7] = f2bf(f1.w);
      bvals[8] = f2bf(f2.x); bvals[9] = f2bf(f2.y); bvals[10] = f2bf(f2.z); bvals[11] = f2bf(f2.w);
      bvals[12] = f2bf(f3.x); bvals[13] = f2bf(f3.y); bvals[14] = f2bf(f3.z); bvals[15] = f2bf(f3.w);
      *(bf16x8*)&Asm[r][kh * 16 + 0] = *(const bf16x8*)&bvals[0];
      *(bf16x8*)&Asm[r][kh * 16 + 8] = *(const bf16x8*)&bvals[8];
      const unsigned short* bsrc = Bt + (size_t)(n0 + r) * (2 * DIM) + k0 + kh * 16;
      *(uint4*)&Bsm[r][kh * 16 + 0] = *(const uint4*)(bsrc);
      *(uint4*)&Bsm[r][kh * 16 + 8] = *(const uint4*)(bsrc + 8);
    }
    __syncthreads();
    bf16x8 af[4], bfr[4];
#pragma unroll
    for (int fm = 0; fm < 4; ++fm)
      af[fm] = *(const bf16x8*)&Asm[wm * 64 + fm * 16 + lr][lk * 8];
#pragma unroll
    for (int fn = 0; fn < 4; ++fn)
      bfr[fn] = *(const bf16x8*)&Bsm[wn * 64 + fn * 16 + lr][lk * 8];
#pragma unroll
    for (int fm = 0; fm < 4; ++fm)
#pragma unroll
      for (int fn = 0; fn < 4; ++fn)
        acc[fm][fn] = __builtin_amdgcn_mfma_f32_16x16x32_bf16(
            af[fm], bfr[fn], acc[fm][fn], 0, 0, 0);
    __syncthreads();
  }
#pragma unroll
  for (int fm = 0; fm < 4; ++fm)
#pragma unroll
    for (int fn = 0; fn < 4; ++fn)
#pragma unroll
      for (int v = 0; v < 4; ++v) {
        int m = m0 + wm * 64 + fm * 16 + lk * 4 + v;
        int n = n0 + wn * 64 + fn * 16 + lr;
        float val = acc[fm][fn][v] + bias[n];
        float g = 0.5f * val * (1.0f + erff(val * 0.70710678f));
        C[(size_t)m * DIM + n] = f2bf(g);
      }
}

// ---------------------------------------------------------------------------
// merged = m1(bf16) @ mrg_w2 + b2 via bf16 MFMA, scattered into out [0,128).
// ---------------------------------------------------------------------------
__global__ __launch_bounds__(256)
void cc_gemm_m2m(const unsigned short* __restrict__ A,
                 const unsigned short* __restrict__ Bt,
                 const float* __restrict__ bias, float* __restrict__ out) {
  __shared__ unsigned short Asm[128][40];
  __shared__ unsigned short Bsm[128][40];
  int tid = threadIdx.x;
  int lane = tid & 63, wave = tid >> 6;
  int wm = wave >> 1, wn = wave & 1;
  int m0 = blockIdx.y * 128, n0 = blockIdx.x * 128;
  int lr = lane & 15, lk = lane >> 4;
  f32x4 acc[4][4] = {};
  const int r = tid >> 1, kh = tid & 1;
  for (int k0 = 0; k0 < DIM; k0 += 32) {
    {
      const unsigned short* src = A + (size_t)(m0 + r) * DIM + k0 + kh * 16;
      *(uint4*)&Asm[r][kh * 16 + 0] = *(const uint4*)(src);
      *(uint4*)&Asm[r][kh * 16 + 8] = *(const uint4*)(src + 8);
      const unsigned short* bsrc = Bt + (size_t)(n0 + r) * DIM + k0 + kh * 16;
      *(uint4*)&Bsm[r][kh * 16 + 0] = *(const uint4*)(bsrc);
      *(uint4*)&Bsm[r][kh * 16 + 8] = *(const uint4*)(bsrc + 8);
    }
    __syncthreads();
    bf16x8 af[4], bfr[4];
#pragma unroll
    for (int fm = 0; fm < 4; ++fm)
      af[fm] = *(const bf16x8*)&Asm[wm * 64 + fm * 16 + lr][lk * 8];
#pragma unroll
    for (int fn = 0; fn < 4; ++fn)
      bfr[fn] = *(const bf16x8*)&Bsm[wn * 64 + fn * 16 + lr][lk * 8];
#pragma unroll
    for (int fm = 0; fm < 4; ++fm)
#pragma unroll
      for (int fn = 0; fn < 4; ++fn)
        acc[fm][fn] = __builtin_amdgcn_mfma_f32_16x16x32_bf16(
            af[fm], bfr[fn], acc[fm][fn], 0, 0, 0);
    __syncthreads();
  }
#pragma unroll
  for (int fm = 0; fm < 4; ++fm)
#pragma unroll
    for (int fn = 0; fn < 4; ++fn)
#pragma unroll
      for (int v = 0; v < 4; ++v) {
        int m = m0 + wm * 64 + fm * 16 + lk * 4 + v;
        int n = n0 + wn * 64 + fn * 16 + lr;
        int bb = m >> 7, p = m & 127;
        float val = acc[fm][fn][v] + bias[n];
        out[((size_t)bb * TLEN + p) * DIM + n] = val;
      }
}

extern "C" void kernel_launch(void* const* d_in, const int* in_sizes, int n_in,
                              void* d_out, int out_size, void* d_ws, size_t ws_size,
                              hipStream_t stream) {
  const float* x      = (const float*)d_in[0];
  const float* imp_w1 = (const float*)d_in[1];
  const float* imp_b1 = (const float*)d_in[2];
  const float* imp_w2 = (const float*)d_in[3];
  const float* imp_b2 = (const float*)d_in[4];
  const float* mrg_w1 = (const float*)d_in[5];
  const float* mrg_b1 = (const float*)d_in[6];
  const float* mrg_w2 = (const float*)d_in[7];
  const float* mrg_b2 = (const float*)d_in[8];
  float* out = (float*)d_out;

  // score (16 MB f32) lives in d_out — fully consumed before output writes.
  float* score = (float*)d_out;

  // workspace: hbuf [0,32MB) during h phase; after imp2 reused for w1t/w2t.
  char* ws = (char*)d_ws;
  float* hbuf  = (float*)ws;                               // 32 MB (h phase)
  unsigned short* w1t = (unsigned short*)ws;               // 16 MB (post-h)
  unsigned short* w2t = (unsigned short*)(ws + ((size_t)16 << 20)); // 8 MB
  unsigned short* m1buf = (unsigned short*)(ws + ((size_t)32 << 20)); // 8 MB bf16
  char* sm = ws + ((size_t)48 << 20);
  float* imp = (float*)sm;              sm += (size_t)BATCH * SEQ * 4;
  float* wv  = (float*)sm;              sm += (size_t)BATCH * SEQ * 4;
  float* rn  = (float*)sm;              sm += (size_t)BATCH * SEQ * 4;
  int* pi    = (int*)sm;                sm += (size_t)BATCH * NPAIRS * 4;
  int* pj    = (int*)sm;                sm += (size_t)BATCH * NPAIRS * 4;
  unsigned char* avail = (unsigned char*)sm; sm += (size_t)BATCH * SEQ;
  int* un    = (int*)sm;                sm += (size_t)BATCH * NUN * 4;
  int* lflag = (int*)sm;                sm += 256;

  cc_probe_f64<<<1, 64, 0, stream>>>(lflag);
  cc_rownorm<<<BATCH * SEQ, 256, 0, stream>>>(x, rn);
  cc_gemm_h<<<dim3(HID / 64, BATCH * SEQ / 128), 256, 0, stream>>>(
      x, imp_w1, imp_b1, hbuf, lflag);
  cc_imp2<<<BATCH * SEQ, 256, 0, stream>>>(hbuf, imp_w2, imp_b2, imp);
  cc_minmax<<<BATCH, 512, 0, stream>>>(imp, wv);
  cc_gemm_score<<<dim3(SEQ / 64, SEQ / 64, BATCH), 256, 0, stream>>>(
      x, rn, wv, score, lflag);
  cc_greedy<<<BATCH, 64, 0, stream>>>(score, pi, pj, avail);
  cc_unmerged<<<BATCH, SEQ, 0, stream>>>(avail, un);
  // hbuf dead; build bf16 transposed weights for the MFMA mergers.
  cc_transpose_bf16<<<dim3(DIM / 32, (2 * DIM) / 32), 256, 0, stream>>>(
      mrg_w1, w1t, 2 * DIM, DIM);
  cc_transpose_bf16<<<dim3(DIM / 32, DIM / 32), 256, 0, stream>>>(
      mrg_w2, w2t, DIM, DIM);
  // score (in d_out) dead from here; start writing outputs.
  cc_unmerged_copy<<<BATCH * NUN, 256, 0, stream>>>(x, un, out);
  cc_gemm_m1m<<<dim3(DIM / 128, BATCH * NPAIRS / 128), 256, 0, stream>>>(
      x, pi, pj, w1t, mrg_b1, m1buf);
  cc_gemm_m2m<<<dim3(DIM / 128, BATCH * NPAIRS / 128), 256, 0, stream>>>(
      m1buf, w2t, mrg_b2, out);
}

// Round 16
// 2925.334 us; speedup vs baseline: 1.4189x; 1.4189x over previous
//
#include <hip/hip_runtime.h>
#include <math.h>

#define BATCH 16
#define SEQ 512
#define DIM 2048
#define HID 1024
#define NPAIRS 128
#define TLEN 384
#define NUN 256

typedef unsigned long long ull;
typedef short bf16x8 __attribute__((ext_vector_type(8)));
typedef float f32x4 __attribute__((ext_vector_type(4)));
typedef double f64x4 __attribute__((ext_vector_type(4)));

__device__ __forceinline__ unsigned short f2bf(float f) {
  unsigned u = __float_as_uint(f);
  unsigned r = (u + 0x7FFFu + ((u >> 16) & 1u)) >> 16;   // RNE
  return (unsigned short)r;
}
__device__ __forceinline__ unsigned ccord(float v) {
  unsigned u = __float_as_uint(v);
  return (u & 0x80000000u) ? ~u : (u | 0x80000000u);
}

// ---------------------------------------------------------------------------
// Probe: determine the v_mfma_f64_16x16x4 D-register layout at runtime.
// (verified working on this HW in rounds 14/15)
// ---------------------------------------------------------------------------
__global__ __launch_bounds__(64)
void cc_probe_f64(int* __restrict__ flag) {
  __shared__ double Af[16][4];
  __shared__ double Bf[4][16];
  int l = threadIdx.x;
  if (l < 16)
#pragma unroll
    for (int k = 0; k < 4; ++k) {
      Af[l][k] = 1.0 + (double)l + 16.0 * k;
      Bf[k][l] = 2.0 + 3.0 * (double)l + 5.0 * k;
    }
  __syncthreads();
  int lr = l & 15, lk = l >> 4;
  double a = Af[lr][lk];
  double b = Bf[lk][lr];
  f64x4 d = {0.0, 0.0, 0.0, 0.0};
  d = __builtin_amdgcn_mfma_f64_16x16x4f64(a, b, d, 0, 0, 0);
  int best = 255;
  for (int H = 0; H < 4; ++H) {
    bool ok = true;
#pragma unroll
    for (int v = 0; v < 4; ++v) {
      int r, c;
      if (H == 0)      { r = 4 * lk + v; c = lr; }
      else if (H == 1) { r = lr; c = 4 * lk + v; }
      else if (H == 2) { r = lk + 4 * v; c = lr; }
      else             { r = lr; c = lk + 4 * v; }
      double tr = 0.0;
#pragma unroll
      for (int k = 0; k < 4; ++k) tr += Af[r][k] * Bf[k][c];
      if (d[v] != tr) ok = false;
    }
    ull m = __ballot(ok);
    if (m == ~0ull) { best = H; break; }
  }
  if (l == 0) *flag = best;
}

// ---------------------------------------------------------------------------
// GEMM 1: h = gelu(x @ imp_w1 + b1). f64 MFMA, 64x64 tile, BK=16 — the
// round-14 proven version (440 us, ~0 bank conflicts). VALU fallback kept.
// ---------------------------------------------------------------------------
__global__ __launch_bounds__(256)
void cc_gemm_h(const float* __restrict__ A, const float* __restrict__ Bw,
               const float* __restrict__ bias, float* __restrict__ C,
               const int* __restrict__ flagp) {
  const int N = HID, K = DIM;
  __shared__ double As[16][66];   // [k][m]
  __shared__ double Bs[16][66];   // [k][n]
  const int H = *flagp;
  int tid = threadIdx.x;
  int lane = tid & 63, wave = tid >> 6;
  int wr = wave >> 1, wc = wave & 1;
  int lr = lane & 15, lk = lane >> 4;
  int pr[4], pc[4];
#pragma unroll
  for (int v = 0; v < 4; ++v) {
    if (H == 0)      { pr[v] = 4 * lk + v; pc[v] = lr; }
    else if (H == 1) { pr[v] = lr; pc[v] = 4 * lk + v; }
    else if (H == 2) { pr[v] = lk + 4 * v; pc[v] = lr; }
    else             { pr[v] = lr; pc[v] = lk + 4 * v; }
  }
  int tx = tid % 16, ty = tid / 16;
  int m0 = blockIdx.y * 64, n0 = blockIdx.x * 64;
  f64x4 acc[2][2] = {{{0.,0.,0.,0.},{0.,0.,0.,0.}},{{0.,0.,0.,0.},{0.,0.,0.,0.}}};
  double vacc[4][4] = {};
  for (int k0 = 0; k0 < K; k0 += 16) {
#pragma unroll
    for (int u = 0; u < 4; ++u) {
      int l = tid + u * 256;
      int r = l >> 4, k = l & 15;
      As[k][r] = (double)A[(size_t)(m0 + r) * K + k0 + k];
      int kb = l >> 6, n = l & 63;
      Bs[kb][n] = (double)Bw[(size_t)(k0 + kb) * N + n0 + n];
    }
    __syncthreads();
    if (H < 4) {
#pragma unroll
      for (int k4 = 0; k4 < 4; ++k4) {
        int kk = k4 * 4 + lk;
        double a0 = As[kk][wr * 32 + lr];
        double a1 = As[kk][wr * 32 + 16 + lr];
        double b0 = Bs[kk][wc * 32 + lr];
        double b1 = Bs[kk][wc * 32 + 16 + lr];
        acc[0][0] = __builtin_amdgcn_mfma_f64_16x16x4f64(a0, b0, acc[0][0], 0, 0, 0);
        acc[0][1] = __builtin_amdgcn_mfma_f64_16x16x4f64(a0, b1, acc[0][1], 0, 0, 0);
        acc[1][0] = __builtin_amdgcn_mfma_f64_16x16x4f64(a1, b0, acc[1][0], 0, 0, 0);
        acc[1][1] = __builtin_amdgcn_mfma_f64_16x16x4f64(a1, b1, acc[1][1], 0, 0, 0);
      }
    } else {
#pragma unroll
      for (int k = 0; k < 16; ++k) {
        double a0 = As[k][ty * 4 + 0], a1 = As[k][ty * 4 + 1];
        double a2 = As[k][ty * 4 + 2], a3 = As[k][ty * 4 + 3];
        double b0 = Bs[k][tx * 4 + 0], b1 = Bs[k][tx * 4 + 1];
        double b2 = Bs[k][tx * 4 + 2], b3 = Bs[k][tx * 4 + 3];
        vacc[0][0] = fma(a0, b0, vacc[0][0]); vacc[0][1] = fma(a0, b1, vacc[0][1]);
        vacc[0][2] = fma(a0, b2, vacc[0][2]); vacc[0][3] = fma(a0, b3, vacc[0][3]);
        vacc[1][0] = fma(a1, b0, vacc[1][0]); vacc[1][1] = fma(a1, b1, vacc[1][1]);
        vacc[1][2] = fma(a1, b2, vacc[1][2]); vacc[1][3] = fma(a1, b3, vacc[1][3]);
        vacc[2][0] = fma(a2, b0, vacc[2][0]); vacc[2][1] = fma(a2, b1, vacc[2][1]);
        vacc[2][2] = fma(a2, b2, vacc[2][2]); vacc[2][3] = fma(a2, b3, vacc[2][3]);
        vacc[3][0] = fma(a3, b0, vacc[3][0]); vacc[3][1] = fma(a3, b1, vacc[3][1]);
        vacc[3][2] = fma(a3, b2, vacc[3][2]); vacc[3][3] = fma(a3, b3, vacc[3][3]);
      }
    }
    __syncthreads();
  }
  if (H < 4) {
#pragma unroll
    for (int i = 0; i < 2; ++i)
#pragma unroll
      for (int j = 0; j < 2; ++j)
#pragma unroll
        for (int v = 0; v < 4; ++v) {
          int m = m0 + wr * 32 + i * 16 + pr[v];
          int n = n0 + wc * 32 + j * 16 + pc[v];
          float pre = (float)(acc[i][j][v] + (double)bias[n]);  // f32 store
          double vv = (double)pre;
          double g = 0.5 * vv * (1.0 + erf(vv * 0.70710678118654752440));
          C[(size_t)m * N + n] = (float)g;                      // f32 store
        }
  } else {
#pragma unroll
    for (int i = 0; i < 4; ++i)
#pragma unroll
      for (int j = 0; j < 4; ++j) {
        int m = m0 + ty * 4 + i, n = n0 + tx * 4 + j;
        float pre = (float)(vacc[i][j] + (double)bias[n]);
        double vv = (double)pre;
        double g = 0.5 * vv * (1.0 + erf(vv * 0.70710678118654752440));
        C[(size_t)m * N + n] = (float)g;
      }
  }
}

// ---------------------------------------------------------------------------
// imp = sigmoid(h @ imp_w2 + b2); logit rounded to f32, imp stored f32
// ---------------------------------------------------------------------------
__global__ __launch_bounds__(256)
void cc_imp2(const float* __restrict__ h, const float* __restrict__ w2,
             const float* __restrict__ b2, float* __restrict__ imp) {
  int row = blockIdx.x, tid = threadIdx.x;
  __shared__ double red[256];
  double s = 0.0;
  const float* hr = h + (size_t)row * HID;
  for (int k = tid; k < HID; k += 256) s = fma((double)hr[k], (double)w2[k], s);
  red[tid] = s;
  __syncthreads();
  for (int off = 128; off > 0; off >>= 1) {
    if (tid < off) red[tid] += red[tid + off];
    __syncthreads();
  }
  if (tid == 0) {
    float logit = (float)(red[0] + (double)b2[0]);          // f32 store point
    double sg = 1.0 / (1.0 + exp(-(double)logit));
    imp[row] = (float)sg;                                   // f32 store point
  }
}

// ---------------------------------------------------------------------------
// per-batch min-max normalize in f32, then w = max(norm, 0.1f)
// ---------------------------------------------------------------------------
__global__ __launch_bounds__(512)
void cc_minmax(const float* __restrict__ imp, float* __restrict__ w) {
  int b = blockIdx.x, tid = threadIdx.x;
  __shared__ float mn[512], mx[512];
  float v = imp[b * SEQ + tid];
  mn[tid] = v; mx[tid] = v;
  __syncthreads();
  for (int off = 256; off > 0; off >>= 1) {
    if (tid < off) {
      mn[tid] = fminf(mn[tid], mn[tid + off]);
      mx[tid] = fmaxf(mx[tid], mx[tid + off]);
    }
    __syncthreads();
  }
  float lo = mn[0], hi = mx[0];
  float nv = (hi > lo) ? (v - lo) / (hi - lo) : v;
  w[b * SEQ + tid] = fmaxf(nv, 0.1f);
}

// ---------------------------------------------------------------------------
// row L2 norms of x: exact f64 sumsq, sqrt, rounded to f32, clamp 1e-12f
// ---------------------------------------------------------------------------
__global__ __launch_bounds__(256)
void cc_rownorm(const float* __restrict__ x, float* __restrict__ rn) {
  int row = blockIdx.x, tid = threadIdx.x;
  __shared__ double red[256];
  double s = 0.0;
  const float* xr = x + (size_t)row * DIM;
  for (int k = tid; k < DIM; k += 256) {
    double v = xr[k];
    s = fma(v, v, s);
  }
  red[tid] = s;
  __syncthreads();
  for (int off = 128; off > 0; off >>= 1) {
    if (tid < off) red[tid] += red[tid + off];
    __syncthreads();
  }
  if (tid == 0) rn[row] = fmaxf((float)sqrt(red[0]), 1e-12f);
}

// ---------------------------------------------------------------------------
// score[b,s,t]: f64 MFMA 64x64 BK=16 + VALU fallback (round-14/15 proven).
// ---------------------------------------------------------------------------
__global__ __launch_bounds__(256)
void cc_gemm_score(const float* __restrict__ X, const float* __restrict__ rn,
                   const float* __restrict__ w, float* __restrict__ score,
                   const int* __restrict__ flagp) {
  const int b = blockIdx.z;
  __shared__ double As[16][66];
  __shared__ double Bs[16][66];
  const int H = *flagp;
  int tid = threadIdx.x;
  int lane = tid & 63, wave = tid >> 6;
  int wr = wave >> 1, wc = wave & 1;
  int lr = lane & 15, lk = lane >> 4;
  int pr[4], pc[4];
#pragma unroll
  for (int v = 0; v < 4; ++v) {
    if (H == 0)      { pr[v] = 4 * lk + v; pc[v] = lr; }
    else if (H == 1) { pr[v] = lr; pc[v] = 4 * lk + v; }
    else if (H == 2) { pr[v] = lk + 4 * v; pc[v] = lr; }
    else             { pr[v] = lr; pc[v] = lk + 4 * v; }
  }
  int tx = tid % 16, ty = tid / 16;
  int s0 = blockIdx.y * 64, t0 = blockIdx.x * 64;
  const float* Xb = X + (size_t)b * SEQ * DIM;
  const float* rnb = rn + b * SEQ;
  f64x4 acc[2][2] = {{{0.,0.,0.,0.},{0.,0.,0.,0.}},{{0.,0.,0.,0.},{0.,0.,0.,0.}}};
  double vacc[4][4] = {};
  for (int k0 = 0; k0 < DIM; k0 += 16) {
#pragma unroll
    for (int u = 0; u < 4; ++u) {
      int l = tid + u * 256;
      int r = l >> 4, k = l & 15;
      As[k][r] = (double)(Xb[(size_t)(s0 + r) * DIM + k0 + k] / rnb[s0 + r]);
      Bs[k][r] = (double)(Xb[(size_t)(t0 + r) * DIM + k0 + k] / rnb[t0 + r]);
    }
    __syncthreads();
    if (H < 4) {
#pragma unroll
      for (int k4 = 0; k4 < 4; ++k4) {
        int kk = k4 * 4 + lk;
        double a0 = As[kk][wr * 32 + lr];
        double a1 = As[kk][wr * 32 + 16 + lr];
        double b0 = Bs[kk][wc * 32 + lr];
        double b1 = Bs[kk][wc * 32 + 16 + lr];
        acc[0][0] = __builtin_amdgcn_mfma_f64_16x16x4f64(a0, b0, acc[0][0], 0, 0, 0);
        acc[0][1] = __builtin_amdgcn_mfma_f64_16x16x4f64(a0, b1, acc[0][1], 0, 0, 0);
        acc[1][0] = __builtin_amdgcn_mfma_f64_16x16x4f64(a1, b0, acc[1][0], 0, 0, 0);
        acc[1][1] = __builtin_amdgcn_mfma_f64_16x16x4f64(a1, b1, acc[1][1], 0, 0, 0);
      }
    } else {
#pragma unroll
      for (int k = 0; k < 16; ++k) {
        double a0 = As[k][ty * 4 + 0], a1 = As[k][ty * 4 + 1];
        double a2 = As[k][ty * 4 + 2], a3 = As[k][ty * 4 + 3];
        double b0 = Bs[k][tx * 4 + 0], b1 = Bs[k][tx * 4 + 1];
        double b2 = Bs[k][tx * 4 + 2], b3 = Bs[k][tx * 4 + 3];
        vacc[0][0] = fma(a0, b0, vacc[0][0]); vacc[0][1] = fma(a0, b1, vacc[0][1]);
        vacc[0][2] = fma(a0, b2, vacc[0][2]); vacc[0][3] = fma(a0, b3, vacc[0][3]);
        vacc[1][0] = fma(a1, b0, vacc[1][0]); vacc[1][1] = fma(a1, b1, vacc[1][1]);
        vacc[1][2] = fma(a1, b2, vacc[1][2]); vacc[1][3] = fma(a1, b3, vacc[1][3]);
        vacc[2][0] = fma(a2, b0, vacc[2][0]); vacc[2][1] = fma(a2, b1, vacc[2][1]);
        vacc[2][2] = fma(a2, b2, vacc[2][2]); vacc[2][3] = fma(a2, b3, vacc[2][3]);
        vacc[3][0] = fma(a3, b0, vacc[3][0]); vacc[3][1] = fma(a3, b1, vacc[3][1]);
        vacc[3][2] = fma(a3, b2, vacc[3][2]); vacc[3][3] = fma(a3, b3, vacc[3][3]);
      }
    }
    __syncthreads();
  }
  if (H < 4) {
#pragma unroll
    for (int i = 0; i < 2; ++i)
#pragma unroll
      for (int j = 0; j < 2; ++j)
#pragma unroll
        for (int v = 0; v < 4; ++v) {
          int s = s0 + wr * 32 + i * 16 + pr[v];
          int t = t0 + wc * 32 + j * 16 + pc[v];
          float vv;
          if (s == t) vv = -1.0f;
          else {
            float sim = (float)acc[i][j][v];                  // f32 store
            float wp = w[b * SEQ + s] * w[b * SEQ + t];       // f32 mul
            vv = sim / wp;                                    // f32 div
          }
          score[((size_t)b * SEQ + s) * SEQ + t] = vv;
        }
  } else {
#pragma unroll
    for (int i = 0; i < 4; ++i)
#pragma unroll
      for (int j = 0; j < 4; ++j) {
        int s = s0 + ty * 4 + i, t = t0 + tx * 4 + j;
        float vv;
        if (s == t) vv = -1.0f;
        else {
          float sim = (float)vacc[i][j];
          float wp = w[b * SEQ + s] * w[b * SEQ + t];
          vv = sim / wp;
        }
        score[((size_t)b * SEQ + s) * SEQ + t] = vv;
      }
  }
}

// ---------------------------------------------------------------------------
// Greedy: ONE WAVE per batch, round-7 structure with u32-chain wave
// reductions (round-15 version, ~500us faster than the u64 chains).
// Tie-breaks identical to flat jnp.argmax.
// ---------------------------------------------------------------------------
__global__ __launch_bounds__(64)
void cc_greedy(const float* __restrict__ score, int* __restrict__ pi,
               int* __restrict__ pj, unsigned char* __restrict__ availg) {
  const int b = blockIdx.x;
  const float* S = score + (size_t)b * SEQ * SEQ;
  const int lane = threadIdx.x;
  __shared__ uint2 availv[SEQ / 8];
  unsigned char* avail = (unsigned char*)availv;
  __shared__ int rargL[SEQ];
  __shared__ int spi[NPAIRS], spj[NPAIRS];
  unsigned rhi8[8];
  int rarg8[8];
  unsigned am = 0xFFu;

  availv[lane] = make_uint2(0x01010101u, 0x01010101u);

  {
    float bv[8]; int bc[8];
#pragma unroll
    for (int q = 0; q < 8; ++q) { bv[q] = -INFINITY; bc[q] = 0; }
    for (int c4 = 0; c4 < SEQ / 4; ++c4) {
#pragma unroll
      for (int q = 0; q < 8; ++q) {
        int r = lane * 8 + q;
        float4 v = ((const float4*)(S + (size_t)r * SEQ))[c4];
        int cc = c4 * 4;
        if (v.x > bv[q]) { bv[q] = v.x; bc[q] = cc; }
        if (v.y > bv[q]) { bv[q] = v.y; bc[q] = cc + 1; }
        if (v.z > bv[q]) { bv[q] = v.z; bc[q] = cc + 2; }
        if (v.w > bv[q]) { bv[q] = v.w; bc[q] = cc + 3; }
      }
    }
#pragma unroll
    for (int q = 0; q < 8; ++q) {
      rhi8[q] = ccord(bv[q]);
      rarg8[q] = bc[q];
      rargL[lane * 8 + q] = bc[q];
    }
  }
  __syncthreads();

  for (int t = 0; t < NPAIRS; ++t) {
    ull key = 0ULL;
#pragma unroll
    for (int q = 0; q < 8; ++q) {
      if (am & (1u << q)) {
        ull k = ((ull)rhi8[q] << 32) | (unsigned)((SEQ - 1) - (lane * 8 + q));
        if (k > key) key = k;
      }
    }
    unsigned myhi = (unsigned)(key >> 32);
    int myrow = (SEQ - 1) - (int)(key & 0xFFFFFFFFull);
    unsigned mx = myhi;
#pragma unroll
    for (int off = 1; off < 64; off <<= 1) {
      unsigned o = __shfl_xor(mx, off, 64);
      if (o > mx) mx = o;
    }
    ull pm = __ballot(myhi == mx);
    int sl = __ffsll(pm) - 1;
    const int i = __shfl(myrow, sl, 64);
    const int j = rargL[i];
    if (lane == 0) {
      spi[t] = i; spj[t] = j;
      avail[i] = 0; avail[j] = 0;
    }
    if ((i >> 3) == lane) am &= ~(1u << (i & 7));
    if ((j >> 3) == lane) am &= ~(1u << (j & 7));
    __syncthreads();

    unsigned needmask = 0u;
#pragma unroll
    for (int q = 0; q < 8; ++q)
      if ((am & (1u << q)) && (rarg8[q] == i || rarg8[q] == j))
        needmask |= (1u << q);
    for (int q = 0; q < 8; ++q) {
      ull m = __ballot((needmask >> q) & 1u);
      while (m) {
        int src = __ffsll(m) - 1;
        m &= m - 1;
        int r = src * 8 + q;
        const float4* row4 = (const float4*)(S + (size_t)r * SEQ) + lane * 2;
        float4 v0 = row4[0], v1 = row4[1];
        uint2 av = availv[lane];
        float nv = -INFINITY; int nc = -1;
        if ((av.x & 0x000000FFu) && v0.x > nv) { nv = v0.x; nc = 0; }
        if ((av.x & 0x0000FF00u) && v0.y > nv) { nv = v0.y; nc = 1; }
        if ((av.x & 0x00FF0000u) && v0.z > nv) { nv = v0.z; nc = 2; }
        if ((av.x & 0xFF000000u) && v0.w > nv) { nv = v0.w; nc = 3; }
        if ((av.y & 0x000000FFu) && v1.x > nv) { nv = v1.x; nc = 4; }
        if ((av.y & 0x0000FF00u) && v1.y > nv) { nv = v1.y; nc = 5; }
        if ((av.y & 0x00FF0000u) && v1.z > nv) { nv = v1.z; nc = 6; }
        if ((av.y & 0xFF000000u) && v1.w > nv) { nv = v1.w; nc = 7; }
        unsigned rhi2 = (nc >= 0) ? ccord(nv) : 0u;
        unsigned mx2 = rhi2;
#pragma unroll
        for (int off = 1; off < 64; off <<= 1) {
          unsigned o = __shfl_xor(mx2, off, 64);
          if (o > mx2) mx2 = o;
        }
        ull pm2 = __ballot(rhi2 == mx2);
        int sl2 = __ffsll(pm2) - 1;
        int gcol = __shfl(lane * 8 + nc, sl2, 64);
        if (lane == src) {
          rhi8[q] = mx2;
          rarg8[q] = gcol;
          rargL[r] = gcol;
        }
      }
    }
    __syncthreads();
  }

  for (int t2 = lane; t2 < NPAIRS; t2 += 64) {
    pi[b * NPAIRS + t2] = spi[t2];
    pj[b * NPAIRS + t2] = spj[t2];
  }
#pragma unroll
  for (int q = 0; q < 8; ++q) {
    int r = lane * 8 + q;
    availg[b * SEQ + r] = avail[r];
  }
}

// ---------------------------------------------------------------------------
// unmerged index list via prefix sum (ascending order)
// ---------------------------------------------------------------------------
__global__ __launch_bounds__(512)
void cc_unmerged(const unsigned char* __restrict__ availg, int* __restrict__ un) {
  int b = blockIdx.x, tid = threadIdx.x;
  __shared__ int ps[SEQ];
  int flag = availg[b * SEQ + tid];
  ps[tid] = flag;
  __syncthreads();
  for (int off = 1; off < SEQ; off <<= 1) {
    int v = (tid >= off) ? ps[tid - off] : 0;
    __syncthreads();
    ps[tid] += v;
    __syncthreads();
  }
  int pos = ps[tid] - flag;
  if (flag && pos < NUN) un[b * NUN + pos] = tid;
}

// ---------------------------------------------------------------------------
// copy unmerged tokens to out rows [128, 384)
// ---------------------------------------------------------------------------
__global__ __launch_bounds__(256)
void cc_unmerged_copy(const float* __restrict__ x, const int* __restrict__ un,
                      float* __restrict__ out) {
  int idx = blockIdx.x;
  int b = idx / NUN, u_ = idx % NUN;
  int s = un[idx];
  const float4* src = (const float4*)(x + ((size_t)b * SEQ + s) * DIM);
  float4* dst = (float4*)(out + ((size_t)b * TLEN + NPAIRS + u_) * DIM);
  for (int u = threadIdx.x; u < DIM / 4; u += 256) dst[u] = src[u];
}

// ---------------------------------------------------------------------------
// W [K][N] f32 row-major -> Wt [N][K] bf16. 32x32 tiles via LDS.
// ---------------------------------------------------------------------------
__global__ __launch_bounds__(256)
void cc_transpose_bf16(const float* __restrict__ W, unsigned short* __restrict__ Wt,
                       int K, int N) {
  __shared__ float t[32][33];
  int tx = threadIdx.x & 31, ty = threadIdx.x >> 5;
  int k0 = blockIdx.y * 32, n0 = blockIdx.x * 32;
#pragma unroll
  for (int u = 0; u < 4; ++u) {
    int kk = ty + u * 8;
    t[kk][tx] = W[(size_t)(k0 + kk) * N + n0 + tx];
  }
  __syncthreads();
#pragma unroll
  for (int u = 0; u < 4; ++u) {
    int nn = ty + u * 8;
    Wt[(size_t)(n0 + nn) * K + k0 + tx] = f2bf(t[tx][nn]);
  }
}

// ---------------------------------------------------------------------------
// m1 = gelu(pair @ mrg_w1 + b1) via bf16 MFMA 16x16x32; OUTPUT bf16.
// ---------------------------------------------------------------------------
__global__ __launch_bounds__(256)
void cc_gemm_m1m(const float* __restrict__ x, const int* __restrict__ pi,
                 const int* __restrict__ pj, const unsigned short* __restrict__ Bt,
                 const float* __restrict__ bias, unsigned short* __restrict__ C) {
  __shared__ unsigned short Asm[128][40];
  __shared__ unsigned short Bsm[128][40];
  int tid = threadIdx.x;
  int lane = tid & 63, wave = tid >> 6;
  int wm = wave >> 1, wn = wave & 1;
  int m0 = blockIdx.y * 128, n0 = blockIdx.x * 128;
  int lr = lane & 15, lk = lane >> 4;
  f32x4 acc[4][4] = {};
  const int r = tid >> 1, kh = tid & 1;
  const int mg = m0 + r;
  const int bb = mg >> 7;
  const int ti_ = pi[mg], tj_ = pj[mg];
  for (int k0 = 0; k0 < 2 * DIM; k0 += 32) {
    {
      int kk = k0 + kh * 16;
      int tok = (kk < DIM) ? ti_ : tj_;
      int kc = (kk < DIM) ? kk : kk - DIM;
      const float* src = x + ((size_t)bb * SEQ + tok) * DIM + kc;
      float4 f0 = *(const float4*)(src);
      float4 f1 = *(const float4*)(src + 4);
      float4 f2 = *(const float4*)(src + 8);
      float4 f3 = *(const float4*)(src + 12);
      unsigned short bvals[16];
      bvals[0] = f2bf(f0.x); bvals[1] = f2bf(f0.y); bvals[2] = f2bf(f0.z); bvals[3] = f2bf(f0.w);
      bvals[4] = f2bf(f1.x); bvals[5] = f2bf(f1.y); bvals[6] = f2bf(f1.z); bvals[7] = f2bf(f1.w);
      bvals[8] = f2bf(f2.x); bvals[9] = f2bf(f2.y); bvals[10] = f2bf(f2.z); bvals[11] = f2bf(f2.w);
      bvals[12] = f2bf(f3.x); bvals[13] = f2bf(f3.y); bvals[14] = f2bf(f3.z); bvals[15] = f2bf(f3.w);
      *(bf16x8*)&Asm[r][kh * 16 + 0] = *(const bf16x8*)&bvals[0];
      *(bf16x8*)&Asm[r][kh * 16 + 8] = *(const bf16x8*)&bvals[8];
      const unsigned short* bsrc = Bt + (size_t)(n0 + r) * (2 * DIM) + k0 + kh * 16;
      *(uint4*)&Bsm[r][kh * 16 + 0] = *(const uint4*)(bsrc);
      *(uint4*)&Bsm[r][kh * 16 + 8] = *(const uint4*)(bsrc + 8);
    }
    __syncthreads();
    bf16x8 af[4], bfr[4];
#pragma unroll
    for (int fm = 0; fm < 4; ++fm)
      af[fm] = *(const bf16x8*)&Asm[wm * 64 + fm * 16 + lr][lk * 8];
#pragma unroll
    for (int fn = 0; fn < 4; ++fn)
      bfr[fn] = *(const bf16x8*)&Bsm[wn * 64 + fn * 16 + lr][lk * 8];
#pragma unroll
    for (int fm = 0; fm < 4; ++fm)
#pragma unroll
      for (int fn = 0; fn < 4; ++fn)
        acc[fm][fn] = __builtin_amdgcn_mfma_f32_16x16x32_bf16(
            af[fm], bfr[fn], acc[fm][fn], 0, 0, 0);
    __syncthreads();
  }
#pragma unroll
  for (int fm = 0; fm < 4; ++fm)
#pragma unroll
    for (int fn = 0; fn < 4; ++fn)
#pragma unroll
      for (int v = 0; v < 4; ++v) {
        int m = m0 + wm * 64 + fm * 16 + lk * 4 + v;
        int n = n0 + wn * 64 + fn * 16 + lr;
        float val = acc[fm][fn][v] + bias[n];
        float g = 0.5f * val * (1.0f + erff(val * 0.70710678f));
        C[(size_t)m * DIM + n] = f2bf(g);
      }
}

// ---------------------------------------------------------------------------
// merged = m1(bf16) @ mrg_w2 + b2 via bf16 MFMA, scattered into out [0,128).
// ---------------------------------------------------------------------------
__global__ __launch_bounds__(256)
void cc_gemm_m2m(const unsigned short* __restrict__ A,
                 const unsigned short* __restrict__ Bt,
                 const float* __restrict__ bias, float* __restrict__ out) {
  __shared__ unsigned short Asm[128][40];
  __shared__ unsigned short Bsm[128][40];
  int tid = threadIdx.x;
  int lane = tid & 63, wave = tid >> 6;
  int wm = wave >> 1, wn = wave & 1;
  int m0 = blockIdx.y * 128, n0 = blockIdx.x * 128;
  int lr = lane & 15, lk = lane >> 4;
  f32x4 acc[4][4] = {};
  const int r = tid >> 1, kh = tid & 1;
  for (int k0 = 0; k0 < DIM; k0 += 32) {
    {
      const unsigned short* src = A + (size_t)(m0 + r) * DIM + k0 + kh * 16;
      *(uint4*)&Asm[r][kh * 16 + 0] = *(const uint4*)(src);
      *(uint4*)&Asm[r][kh * 16 + 8] = *(const uint4*)(src + 8);
      const unsigned short* bsrc = Bt + (size_t)(n0 + r) * DIM + k0 + kh * 16;
      *(uint4*)&Bsm[r][kh * 16 + 0] = *(const uint4*)(bsrc);
      *(uint4*)&Bsm[r][kh * 16 + 8] = *(const uint4*)(bsrc + 8);
    }
    __syncthreads();
    bf16x8 af[4], bfr[4];
#pragma unroll
    for (int fm = 0; fm < 4; ++fm)
      af[fm] = *(const bf16x8*)&Asm[wm * 64 + fm * 16 + lr][lk * 8];
#pragma unroll
    for (int fn = 0; fn < 4; ++fn)
      bfr[fn] = *(const bf16x8*)&Bsm[wn * 64 + fn * 16 + lr][lk * 8];
#pragma unroll
    for (int fm = 0; fm < 4; ++fm)
#pragma unroll
      for (int fn = 0; fn < 4; ++fn)
        acc[fm][fn] = __builtin_amdgcn_mfma_f32_16x16x32_bf16(
            af[fm], bfr[fn], acc[fm][fn], 0, 0, 0);
    __syncthreads();
  }
#pragma unroll
  for (int fm = 0; fm < 4; ++fm)
#pragma unroll
    for (int fn = 0; fn < 4; ++fn)
#pragma unroll
      for (int v = 0; v < 4; ++v) {
        int m = m0 + wm * 64 + fm * 16 + lk * 4 + v;
        int n = n0 + wn * 64 + fn * 16 + lr;
        int bb = m >> 7, p = m & 127;
        float val = acc[fm][fn][v] + bias[n];
        out[((size_t)bb * TLEN + p) * DIM + n] = val;
      }
}

extern "C" void kernel_launch(void* const* d_in, const int* in_sizes, int n_in,
                              void* d_out, int out_size, void* d_ws, size_t ws_size,
                              hipStream_t stream) {
  const float* x      = (const float*)d_in[0];
  const float* imp_w1 = (const float*)d_in[1];
  const float* imp_b1 = (const float*)d_in[2];
  const float* imp_w2 = (const float*)d_in[3];
  const float* imp_b2 = (const float*)d_in[4];
  const float* mrg_w1 = (const float*)d_in[5];
  const float* mrg_b1 = (const float*)d_in[6];
  const float* mrg_w2 = (const float*)d_in[7];
  const float* mrg_b2 = (const float*)d_in[8];
  float* out = (float*)d_out;

  // score (16 MB f32) lives in d_out — fully consumed before output writes.
  float* score = (float*)d_out;

  // workspace: hbuf [0,32MB) during h phase; after imp2 reused for w1t/w2t.
  char* ws = (char*)d_ws;
  float* hbuf  = (float*)ws;                               // 32 MB (h phase)
  unsigned short* w1t = (unsigned short*)ws;               // 16 MB (post-h)
  unsigned short* w2t = (unsigned short*)(ws + ((size_t)16 << 20)); // 8 MB
  unsigned short* m1buf = (unsigned short*)(ws + ((size_t)32 << 20)); // 8 MB bf16
  char* sm = ws + ((size_t)48 << 20);
  float* imp = (float*)sm;              sm += (size_t)BATCH * SEQ * 4;
  float* wv  = (float*)sm;              sm += (size_t)BATCH * SEQ * 4;
  float* rn  = (float*)sm;              sm += (size_t)BATCH * SEQ * 4;
  int* pi    = (int*)sm;                sm += (size_t)BATCH * NPAIRS * 4;
  int* pj    = (int*)sm;                sm += (size_t)BATCH * NPAIRS * 4;
  unsigned char* avail = (unsigned char*)sm; sm += (size_t)BATCH * SEQ;
  int* un    = (int*)sm;                sm += (size_t)BATCH * NUN * 4;
  int* lflag = (int*)sm;                sm += 256;

  cc_probe_f64<<<1, 64, 0, stream>>>(lflag);
  cc_rownorm<<<BATCH * SEQ, 256, 0, stream>>>(x, rn);
  cc_gemm_h<<<dim3(HID / 64, BATCH * SEQ / 64), 256, 0, stream>>>(
      x, imp_w1, imp_b1, hbuf, lflag);
  cc_imp2<<<BATCH * SEQ, 256, 0, stream>>>(hbuf, imp_w2, imp_b2, imp);
  cc_minmax<<<BATCH, 512, 0, stream>>>(imp, wv);
  cc_gemm_score<<<dim3(SEQ / 64, SEQ / 64, BATCH), 256, 0, stream>>>(
      x, rn, wv, score, lflag);
  cc_greedy<<<BATCH, 64, 0, stream>>>(score, pi, pj, avail);
  cc_unmerged<<<BATCH, SEQ, 0, stream>>>(avail, un);
  // hbuf dead; build bf16 transposed weights for the MFMA mergers.
  cc_transpose_bf16<<<dim3(DIM / 32, (2 * DIM) / 32), 256, 0, stream>>>(
      mrg_w1, w1t, 2 * DIM, DIM);
  cc_transpose_bf16<<<dim3(DIM / 32, DIM / 32), 256, 0, stream>>>(
      mrg_w2, w2t, DIM, DIM);
  // score (in d_out) dead from here; start writing outputs.
  cc_unmerged_copy<<<BATCH * NUN, 256, 0, stream>>>(x, un, out);
  cc_gemm_m1m<<<dim3(DIM / 128, BATCH * NPAIRS / 128), 256, 0, stream>>>(
      x, pi, pj, w1t, mrg_b1, m1buf);
  cc_gemm_m2m<<<dim3(DIM / 128, BATCH * NPAIRS / 128), 256, 0, stream>>>(
      m1buf, w2t, mrg_b2, out);
}

// Round 17
// 2620.063 us; speedup vs baseline: 1.5843x; 1.1165x over previous
//
#include <hip/hip_runtime.h>
#include <math.h>

#define BATCH 16
#define SEQ 512
#define DIM 2048
#define HID 1024
#define NPAIRS 128
#define TLEN 384
#define NUN 256

typedef unsigned long long ull;
typedef short bf16x8 __attribute__((ext_vector_type(8)));
typedef float f32x4 __attribute__((ext_vector_type(4)));
typedef double f64x4 __attribute__((ext_vector_type(4)));

__device__ __forceinline__ unsigned short f2bf(float f) {
  unsigned u = __float_as_uint(f);
  unsigned r = (u + 0x7FFFu + ((u >> 16) & 1u)) >> 16;   // RNE
  return (unsigned short)r;
}
__device__ __forceinline__ unsigned ccord(float v) {
  unsigned u = __float_as_uint(v);
  return (u & 0x80000000u) ? ~u : (u | 0x80000000u);
}

// ---------------------------------------------------------------------------
// Probe: determine the v_mfma_f64_16x16x4 D-register layout at runtime.
// (verified working on this HW in rounds 14-16)
// ---------------------------------------------------------------------------
__global__ __launch_bounds__(64)
void cc_probe_f64(int* __restrict__ flag) {
  __shared__ double Af[16][4];
  __shared__ double Bf[4][16];
  int l = threadIdx.x;
  if (l < 16)
#pragma unroll
    for (int k = 0; k < 4; ++k) {
      Af[l][k] = 1.0 + (double)l + 16.0 * k;
      Bf[k][l] = 2.0 + 3.0 * (double)l + 5.0 * k;
    }
  __syncthreads();
  int lr = l & 15, lk = l >> 4;
  double a = Af[lr][lk];
  double b = Bf[lk][lr];
  f64x4 d = {0.0, 0.0, 0.0, 0.0};
  d = __builtin_amdgcn_mfma_f64_16x16x4f64(a, b, d, 0, 0, 0);
  int best = 255;
  for (int H = 0; H < 4; ++H) {
    bool ok = true;
#pragma unroll
    for (int v = 0; v < 4; ++v) {
      int r, c;
      if (H == 0)      { r = 4 * lk + v; c = lr; }
      else if (H == 1) { r = lr; c = 4 * lk + v; }
      else if (H == 2) { r = lk + 4 * v; c = lr; }
      else             { r = lr; c = lk + 4 * v; }
      double tr = 0.0;
#pragma unroll
      for (int k = 0; k < 4; ++k) tr += Af[r][k] * Bf[k][c];
      if (d[v] != tr) ok = false;
    }
    ull m = __ballot(ok);
    if (m == ~0ull) { best = H; break; }
  }
  if (l == 0) *flag = best;
}

// ---------------------------------------------------------------------------
// GEMM 1: h = gelu(x @ imp_w1 + b1). f64 MFMA, 64x64 tile, BK=16 (round-14
// proven). VALU fallback kept.
// ---------------------------------------------------------------------------
__global__ __launch_bounds__(256)
void cc_gemm_h(const float* __restrict__ A, const float* __restrict__ Bw,
               const float* __restrict__ bias, float* __restrict__ C,
               const int* __restrict__ flagp) {
  const int N = HID, K = DIM;
  __shared__ double As[16][66];   // [k][m]
  __shared__ double Bs[16][66];   // [k][n]
  const int H = *flagp;
  int tid = threadIdx.x;
  int lane = tid & 63, wave = tid >> 6;
  int wr = wave >> 1, wc = wave & 1;
  int lr = lane & 15, lk = lane >> 4;
  int pr[4], pc[4];
#pragma unroll
  for (int v = 0; v < 4; ++v) {
    if (H == 0)      { pr[v] = 4 * lk + v; pc[v] = lr; }
    else if (H == 1) { pr[v] = lr; pc[v] = 4 * lk + v; }
    else if (H == 2) { pr[v] = lk + 4 * v; pc[v] = lr; }
    else             { pr[v] = lr; pc[v] = lk + 4 * v; }
  }
  int tx = tid % 16, ty = tid / 16;
  int m0 = blockIdx.y * 64, n0 = blockIdx.x * 64;
  f64x4 acc[2][2] = {{{0.,0.,0.,0.},{0.,0.,0.,0.}},{{0.,0.,0.,0.},{0.,0.,0.,0.}}};
  double vacc[4][4] = {};
  for (int k0 = 0; k0 < K; k0 += 16) {
#pragma unroll
    for (int u = 0; u < 4; ++u) {
      int l = tid + u * 256;
      int r = l >> 4, k = l & 15;
      As[k][r] = (double)A[(size_t)(m0 + r) * K + k0 + k];
      int kb = l >> 6, n = l & 63;
      Bs[kb][n] = (double)Bw[(size_t)(k0 + kb) * N + n0 + n];
    }
    __syncthreads();
    if (H < 4) {
#pragma unroll
      for (int k4 = 0; k4 < 4; ++k4) {
        int kk = k4 * 4 + lk;
        double a0 = As[kk][wr * 32 + lr];
        double a1 = As[kk][wr * 32 + 16 + lr];
        double b0 = Bs[kk][wc * 32 + lr];
        double b1 = Bs[kk][wc * 32 + 16 + lr];
        acc[0][0] = __builtin_amdgcn_mfma_f64_16x16x4f64(a0, b0, acc[0][0], 0, 0, 0);
        acc[0][1] = __builtin_amdgcn_mfma_f64_16x16x4f64(a0, b1, acc[0][1], 0, 0, 0);
        acc[1][0] = __builtin_amdgcn_mfma_f64_16x16x4f64(a1, b0, acc[1][0], 0, 0, 0);
        acc[1][1] = __builtin_amdgcn_mfma_f64_16x16x4f64(a1, b1, acc[1][1], 0, 0, 0);
      }
    } else {
#pragma unroll
      for (int k = 0; k < 16; ++k) {
        double a0 = As[k][ty * 4 + 0], a1 = As[k][ty * 4 + 1];
        double a2 = As[k][ty * 4 + 2], a3 = As[k][ty * 4 + 3];
        double b0 = Bs[k][tx * 4 + 0], b1 = Bs[k][tx * 4 + 1];
        double b2 = Bs[k][tx * 4 + 2], b3 = Bs[k][tx * 4 + 3];
        vacc[0][0] = fma(a0, b0, vacc[0][0]); vacc[0][1] = fma(a0, b1, vacc[0][1]);
        vacc[0][2] = fma(a0, b2, vacc[0][2]); vacc[0][3] = fma(a0, b3, vacc[0][3]);
        vacc[1][0] = fma(a1, b0, vacc[1][0]); vacc[1][1] = fma(a1, b1, vacc[1][1]);
        vacc[1][2] = fma(a1, b2, vacc[1][2]); vacc[1][3] = fma(a1, b3, vacc[1][3]);
        vacc[2][0] = fma(a2, b0, vacc[2][0]); vacc[2][1] = fma(a2, b1, vacc[2][1]);
        vacc[2][2] = fma(a2, b2, vacc[2][2]); vacc[2][3] = fma(a2, b3, vacc[2][3]);
        vacc[3][0] = fma(a3, b0, vacc[3][0]); vacc[3][1] = fma(a3, b1, vacc[3][1]);
        vacc[3][2] = fma(a3, b2, vacc[3][2]); vacc[3][3] = fma(a3, b3, vacc[3][3]);
      }
    }
    __syncthreads();
  }
  if (H < 4) {
#pragma unroll
    for (int i = 0; i < 2; ++i)
#pragma unroll
      for (int j = 0; j < 2; ++j)
#pragma unroll
        for (int v = 0; v < 4; ++v) {
          int m = m0 + wr * 32 + i * 16 + pr[v];
          int n = n0 + wc * 32 + j * 16 + pc[v];
          float pre = (float)(acc[i][j][v] + (double)bias[n]);  // f32 store
          double vv = (double)pre;
          double g = 0.5 * vv * (1.0 + erf(vv * 0.70710678118654752440));
          C[(size_t)m * N + n] = (float)g;                      // f32 store
        }
  } else {
#pragma unroll
    for (int i = 0; i < 4; ++i)
#pragma unroll
      for (int j = 0; j < 4; ++j) {
        int m = m0 + ty * 4 + i, n = n0 + tx * 4 + j;
        float pre = (float)(vacc[i][j] + (double)bias[n]);
        double vv = (double)pre;
        double g = 0.5 * vv * (1.0 + erf(vv * 0.70710678118654752440));
        C[(size_t)m * N + n] = (float)g;
      }
  }
}

// ---------------------------------------------------------------------------
// imp = sigmoid(h @ imp_w2 + b2); logit rounded to f32, imp stored f32
// ---------------------------------------------------------------------------
__global__ __launch_bounds__(256)
void cc_imp2(const float* __restrict__ h, const float* __restrict__ w2,
             const float* __restrict__ b2, float* __restrict__ imp) {
  int row = blockIdx.x, tid = threadIdx.x;
  __shared__ double red[256];
  double s = 0.0;
  const float* hr = h + (size_t)row * HID;
  for (int k = tid; k < HID; k += 256) s = fma((double)hr[k], (double)w2[k], s);
  red[tid] = s;
  __syncthreads();
  for (int off = 128; off > 0; off >>= 1) {
    if (tid < off) red[tid] += red[tid + off];
    __syncthreads();
  }
  if (tid == 0) {
    float logit = (float)(red[0] + (double)b2[0]);          // f32 store point
    double sg = 1.0 / (1.0 + exp(-(double)logit));
    imp[row] = (float)sg;                                   // f32 store point
  }
}

// ---------------------------------------------------------------------------
// per-batch min-max normalize in f32, then w = max(norm, 0.1f)
// ---------------------------------------------------------------------------
__global__ __launch_bounds__(512)
void cc_minmax(const float* __restrict__ imp, float* __restrict__ w) {
  int b = blockIdx.x, tid = threadIdx.x;
  __shared__ float mn[512], mx[512];
  float v = imp[b * SEQ + tid];
  mn[tid] = v; mx[tid] = v;
  __syncthreads();
  for (int off = 256; off > 0; off >>= 1) {
    if (tid < off) {
      mn[tid] = fminf(mn[tid], mn[tid + off]);
      mx[tid] = fmaxf(mx[tid], mx[tid + off]);
    }
    __syncthreads();
  }
  float lo = mn[0], hi = mx[0];
  float nv = (hi > lo) ? (v - lo) / (hi - lo) : v;
  w[b * SEQ + tid] = fmaxf(nv, 0.1f);
}

// ---------------------------------------------------------------------------
// row L2 norms of x: exact f64 sumsq, sqrt, rounded to f32, clamp 1e-12f
// ---------------------------------------------------------------------------
__global__ __launch_bounds__(256)
void cc_rownorm(const float* __restrict__ x, float* __restrict__ rn) {
  int row = blockIdx.x, tid = threadIdx.x;
  __shared__ double red[256];
  double s = 0.0;
  const float* xr = x + (size_t)row * DIM;
  for (int k = tid; k < DIM; k += 256) {
    double v = xr[k];
    s = fma(v, v, s);
  }
  red[tid] = s;
  __syncthreads();
  for (int off = 128; off > 0; off >>= 1) {
    if (tid < off) red[tid] += red[tid + off];
    __syncthreads();
  }
  if (tid == 0) rn[row] = fmaxf((float)sqrt(red[0]), 1e-12f);
}

// ---------------------------------------------------------------------------
// score[b,s,t]: f64 MFMA 64x64 BK=16 + VALU fallback (round-14/16 proven).
// ---------------------------------------------------------------------------
__global__ __launch_bounds__(256)
void cc_gemm_score(const float* __restrict__ X, const float* __restrict__ rn,
                   const float* __restrict__ w, float* __restrict__ score,
                   const int* __restrict__ flagp) {
  const int b = blockIdx.z;
  __shared__ double As[16][66];
  __shared__ double Bs[16][66];
  const int H = *flagp;
  int tid = threadIdx.x;
  int lane = tid & 63, wave = tid >> 6;
  int wr = wave >> 1, wc = wave & 1;
  int lr = lane & 15, lk = lane >> 4;
  int pr[4], pc[4];
#pragma unroll
  for (int v = 0; v < 4; ++v) {
    if (H == 0)      { pr[v] = 4 * lk + v; pc[v] = lr; }
    else if (H == 1) { pr[v] = lr; pc[v] = 4 * lk + v; }
    else if (H == 2) { pr[v] = lk + 4 * v; pc[v] = lr; }
    else             { pr[v] = lr; pc[v] = lk + 4 * v; }
  }
  int tx = tid % 16, ty = tid / 16;
  int s0 = blockIdx.y * 64, t0 = blockIdx.x * 64;
  const float* Xb = X + (size_t)b * SEQ * DIM;
  const float* rnb = rn + b * SEQ;
  f64x4 acc[2][2] = {{{0.,0.,0.,0.},{0.,0.,0.,0.}},{{0.,0.,0.,0.},{0.,0.,0.,0.}}};
  double vacc[4][4] = {};
  for (int k0 = 0; k0 < DIM; k0 += 16) {
#pragma unroll
    for (int u = 0; u < 4; ++u) {
      int l = tid + u * 256;
      int r = l >> 4, k = l & 15;
      As[k][r] = (double)(Xb[(size_t)(s0 + r) * DIM + k0 + k] / rnb[s0 + r]);
      Bs[k][r] = (double)(Xb[(size_t)(t0 + r) * DIM + k0 + k] / rnb[t0 + r]);
    }
    __syncthreads();
    if (H < 4) {
#pragma unroll
      for (int k4 = 0; k4 < 4; ++k4) {
        int kk = k4 * 4 + lk;
        double a0 = As[kk][wr * 32 + lr];
        double a1 = As[kk][wr * 32 + 16 + lr];
        double b0 = Bs[kk][wc * 32 + lr];
        double b1 = Bs[kk][wc * 32 + 16 + lr];
        acc[0][0] = __builtin_amdgcn_mfma_f64_16x16x4f64(a0, b0, acc[0][0], 0, 0, 0);
        acc[0][1] = __builtin_amdgcn_mfma_f64_16x16x4f64(a0, b1, acc[0][1], 0, 0, 0);
        acc[1][0] = __builtin_amdgcn_mfma_f64_16x16x4f64(a1, b0, acc[1][0], 0, 0, 0);
        acc[1][1] = __builtin_amdgcn_mfma_f64_16x16x4f64(a1, b1, acc[1][1], 0, 0, 0);
      }
    } else {
#pragma unroll
      for (int k = 0; k < 16; ++k) {
        double a0 = As[k][ty * 4 + 0], a1 = As[k][ty * 4 + 1];
        double a2 = As[k][ty * 4 + 2], a3 = As[k][ty * 4 + 3];
        double b0 = Bs[k][tx * 4 + 0], b1 = Bs[k][tx * 4 + 1];
        double b2 = Bs[k][tx * 4 + 2], b3 = Bs[k][tx * 4 + 3];
        vacc[0][0] = fma(a0, b0, vacc[0][0]); vacc[0][1] = fma(a0, b1, vacc[0][1]);
        vacc[0][2] = fma(a0, b2, vacc[0][2]); vacc[0][3] = fma(a0, b3, vacc[0][3]);
        vacc[1][0] = fma(a1, b0, vacc[1][0]); vacc[1][1] = fma(a1, b1, vacc[1][1]);
        vacc[1][2] = fma(a1, b2, vacc[1][2]); vacc[1][3] = fma(a1, b3, vacc[1][3]);
        vacc[2][0] = fma(a2, b0, vacc[2][0]); vacc[2][1] = fma(a2, b1, vacc[2][1]);
        vacc[2][2] = fma(a2, b2, vacc[2][2]); vacc[2][3] = fma(a2, b3, vacc[2][3]);
        vacc[3][0] = fma(a3, b0, vacc[3][0]); vacc[3][1] = fma(a3, b1, vacc[3][1]);
        vacc[3][2] = fma(a3, b2, vacc[3][2]); vacc[3][3] = fma(a3, b3, vacc[3][3]);
      }
    }
    __syncthreads();
  }
  if (H < 4) {
#pragma unroll
    for (int i = 0; i < 2; ++i)
#pragma unroll
      for (int j = 0; j < 2; ++j)
#pragma unroll
        for (int v = 0; v < 4; ++v) {
          int s = s0 + wr * 32 + i * 16 + pr[v];
          int t = t0 + wc * 32 + j * 16 + pc[v];
          float vv;
          if (s == t) vv = -1.0f;
          else {
            float sim = (float)acc[i][j][v];                  // f32 store
            float wp = w[b * SEQ + s] * w[b * SEQ + t];       // f32 mul
            vv = sim / wp;                                    // f32 div
          }
          score[((size_t)b * SEQ + s) * SEQ + t] = vv;
        }
  } else {
#pragma unroll
    for (int i = 0; i < 4; ++i)
#pragma unroll
      for (int j = 0; j < 4; ++j) {
        int s = s0 + ty * 4 + i, t = t0 + tx * 4 + j;
        float vv;
        if (s == t) vv = -1.0f;
        else {
          float sim = (float)vacc[i][j];
          float wp = w[b * SEQ + s] * w[b * SEQ + t];
          vv = sim / wp;
        }
        score[((size_t)b * SEQ + s) * SEQ + t] = vv;
      }
  }
}

// ---------------------------------------------------------------------------
// Greedy: ONE WAVE per batch, round-7/16 pick structure UNCHANGED. Refresh
// restructured: needy rows compacted into Rlist (ballot-prefix), then
// processed 4-per-batch with loads issued up-front and the 6 reduction
// stages interleaved across rows (independent shfls pipeline through the
// LDS-permute unit). Tie-breaks identical to flat jnp.argmax.
// ---------------------------------------------------------------------------
__global__ __launch_bounds__(64)
void cc_greedy(const float* __restrict__ score, int* __restrict__ pi,
               int* __restrict__ pj, unsigned char* __restrict__ availg) {
  const int b = blockIdx.x;
  const float* S = score + (size_t)b * SEQ * SEQ;
  const int lane = threadIdx.x;
  __shared__ uint2 availv[SEQ / 8];
  unsigned char* avail = (unsigned char*)availv;
  __shared__ int rargL[SEQ];
  __shared__ int Rlist[SEQ];
  __shared__ int spi[NPAIRS], spj[NPAIRS];
  unsigned rhi8[8];
  int rarg8[8];
  unsigned am = 0xFFu;

  availv[lane] = make_uint2(0x01010101u, 0x01010101u);

  // ---- init: 8 independent row scans per lane ----
  {
    float bv[8]; int bc[8];
#pragma unroll
    for (int q = 0; q < 8; ++q) { bv[q] = -INFINITY; bc[q] = 0; }
    for (int c4 = 0; c4 < SEQ / 4; ++c4) {
#pragma unroll
      for (int q = 0; q < 8; ++q) {
        int r = lane * 8 + q;
        float4 v = ((const float4*)(S + (size_t)r * SEQ))[c4];
        int cc = c4 * 4;
        if (v.x > bv[q]) { bv[q] = v.x; bc[q] = cc; }
        if (v.y > bv[q]) { bv[q] = v.y; bc[q] = cc + 1; }
        if (v.z > bv[q]) { bv[q] = v.z; bc[q] = cc + 2; }
        if (v.w > bv[q]) { bv[q] = v.w; bc[q] = cc + 3; }
      }
    }
#pragma unroll
    for (int q = 0; q < 8; ++q) {
      rhi8[q] = ccord(bv[q]);
      rarg8[q] = bc[q];
      rargL[lane * 8 + q] = bc[q];
    }
  }
  __syncthreads();

  for (int t = 0; t < NPAIRS; ++t) {
    // ---- pick (round-16 u32-chain, unchanged) ----
    ull key = 0ULL;
#pragma unroll
    for (int q = 0; q < 8; ++q) {
      if (am & (1u << q)) {
        ull k = ((ull)rhi8[q] << 32) | (unsigned)((SEQ - 1) - (lane * 8 + q));
        if (k > key) key = k;
      }
    }
    unsigned myhi = (unsigned)(key >> 32);
    int myrow = (SEQ - 1) - (int)(key & 0xFFFFFFFFull);
    unsigned mxp = myhi;
#pragma unroll
    for (int off = 1; off < 64; off <<= 1) {
      unsigned o = __shfl_xor(mxp, off, 64);
      if (o > mxp) mxp = o;
    }
    ull pm = __ballot(myhi == mxp);
    int sl = __ffsll(pm) - 1;
    const int i = __shfl(myrow, sl, 64);
    const int j = rargL[i];
    if (lane == 0) {
      spi[t] = i; spj[t] = j;
      avail[i] = 0; avail[j] = 0;
    }
    if ((i >> 3) == lane) am &= ~(1u << (i & 7));
    if ((j >> 3) == lane) am &= ~(1u << (j & 7));
    __syncthreads();

    // ---- compact needy rows into Rlist (ballot-prefix, no atomics) ----
    int cbase = 0;
#pragma unroll
    for (int q = 0; q < 8; ++q) {
      bool need = (am & (1u << q)) && (rarg8[q] == i || rarg8[q] == j);
      ull mask = __ballot(need);
      if (need) {
        int pos = __popcll(mask & ((1ull << lane) - 1ull));
        Rlist[cbase + pos] = lane * 8 + q;
      }
      cbase += (int)__popcll(mask);
    }
    const int cnt = cbase;
    __syncthreads();

    // ---- batched refresh: 4 rows/batch, loads up-front, interleaved reduce
    const uint2 av = availv[lane];
    for (int base = 0; base < cnt; base += 4) {
      const int nb = (cnt - base < 4) ? (cnt - base) : 4;
      int rr[4]; float4 va[4], vb[4];
#pragma unroll
      for (int u = 0; u < 4; ++u) {
        if (u < nb) {
          rr[u] = Rlist[base + u];
          const float4* p = (const float4*)(S + (size_t)rr[u] * SEQ) + lane * 2;
          va[u] = p[0]; vb[u] = p[1];
        } else rr[u] = -1;
      }
      unsigned loc[4]; int ncl[4];
#pragma unroll
      for (int u = 0; u < 4; ++u) {
        float nv = -INFINITY; int nc = -1;
        if (u < nb) {
          if ((av.x & 0x000000FFu) && va[u].x > nv) { nv = va[u].x; nc = 0; }
          if ((av.x & 0x0000FF00u) && va[u].y > nv) { nv = va[u].y; nc = 1; }
          if ((av.x & 0x00FF0000u) && va[u].z > nv) { nv = va[u].z; nc = 2; }
          if ((av.x & 0xFF000000u) && va[u].w > nv) { nv = va[u].w; nc = 3; }
          if ((av.y & 0x000000FFu) && vb[u].x > nv) { nv = vb[u].x; nc = 4; }
          if ((av.y & 0x0000FF00u) && vb[u].y > nv) { nv = vb[u].y; nc = 5; }
          if ((av.y & 0x00FF0000u) && vb[u].z > nv) { nv = vb[u].z; nc = 6; }
          if ((av.y & 0xFF000000u) && vb[u].w > nv) { nv = vb[u].w; nc = 7; }
        }
        loc[u] = (nc >= 0) ? ccord(nv) : 0u;
        ncl[u] = lane * 8 + nc;
      }
      unsigned mx0 = loc[0], mx1 = loc[1], mx2 = loc[2], mx3 = loc[3];
#pragma unroll
      for (int off = 1; off < 64; off <<= 1) {
        unsigned o0 = __shfl_xor(mx0, off, 64);
        unsigned o1 = __shfl_xor(mx1, off, 64);
        unsigned o2 = __shfl_xor(mx2, off, 64);
        unsigned o3 = __shfl_xor(mx3, off, 64);
        if (o0 > mx0) mx0 = o0;
        if (o1 > mx1) mx1 = o1;
        if (o2 > mx2) mx2 = o2;
        if (o3 > mx3) mx3 = o3;
      }
      unsigned mxa[4] = {mx0, mx1, mx2, mx3};
#pragma unroll
      for (int u = 0; u < 4; ++u) {
        if (u < nb) {
          ull pm2 = __ballot(loc[u] == mxa[u]);
          int sl2 = __ffsll(pm2) - 1;
          int gcol = __shfl(ncl[u], sl2, 64);
          if ((rr[u] >> 3) == lane) {
            int qq = rr[u] & 7;
#pragma unroll
            for (int q = 0; q < 8; ++q)
              if (q == qq) { rhi8[q] = mxa[u]; rarg8[q] = gcol; }
            rargL[rr[u]] = gcol;
          }
        }
      }
    }
    __syncthreads();
  }

  for (int t2 = lane; t2 < NPAIRS; t2 += 64) {
    pi[b * NPAIRS + t2] = spi[t2];
    pj[b * NPAIRS + t2] = spj[t2];
  }
#pragma unroll
  for (int q = 0; q < 8; ++q) {
    int r = lane * 8 + q;
    availg[b * SEQ + r] = avail[r];
  }
}

// ---------------------------------------------------------------------------
// unmerged index list via prefix sum (ascending order)
// ---------------------------------------------------------------------------
__global__ __launch_bounds__(512)
void cc_unmerged(const unsigned char* __restrict__ availg, int* __restrict__ un) {
  int b = blockIdx.x, tid = threadIdx.x;
  __shared__ int ps[SEQ];
  int flag = availg[b * SEQ + tid];
  ps[tid] = flag;
  __syncthreads();
  for (int off = 1; off < SEQ; off <<= 1) {
    int v = (tid >= off) ? ps[tid - off] : 0;
    __syncthreads();
    ps[tid] += v;
    __syncthreads();
  }
  int pos = ps[tid] - flag;
  if (flag && pos < NUN) un[b * NUN + pos] = tid;
}

// ---------------------------------------------------------------------------
// copy unmerged tokens to out rows [128, 384)
// ---------------------------------------------------------------------------
__global__ __launch_bounds__(256)
void cc_unmerged_copy(const float* __restrict__ x, const int* __restrict__ un,
                      float* __restrict__ out) {
  int idx = blockIdx.x;
  int b = idx / NUN, u_ = idx % NUN;
  int s = un[idx];
  const float4* src = (const float4*)(x + ((size_t)b * SEQ + s) * DIM);
  float4* dst = (float4*)(out + ((size_t)b * TLEN + NPAIRS + u_) * DIM);
  for (int u = threadIdx.x; u < DIM / 4; u += 256) dst[u] = src[u];
}

// ---------------------------------------------------------------------------
// W [K][N] f32 row-major -> Wt [N][K] bf16. 32x32 tiles via LDS.
// ---------------------------------------------------------------------------
__global__ __launch_bounds__(256)
void cc_transpose_bf16(const float* __restrict__ W, unsigned short* __restrict__ Wt,
                       int K, int N) {
  __shared__ float t[32][33];
  int tx = threadIdx.x & 31, ty = threadIdx.x >> 5;
  int k0 = blockIdx.y * 32, n0 = blockIdx.x * 32;
#pragma unroll
  for (int u = 0; u < 4; ++u) {
    int kk = ty + u * 8;
    t[kk][tx] = W[(size_t)(k0 + kk) * N + n0 + tx];
  }
  __syncthreads();
#pragma unroll
  for (int u = 0; u < 4; ++u) {
    int nn = ty + u * 8;
    Wt[(size_t)(n0 + nn) * K + k0 + tx] = f2bf(t[tx][nn]);
  }
}

// ---------------------------------------------------------------------------
// m1 = gelu(pair @ mrg_w1 + b1) via bf16 MFMA 16x16x32; OUTPUT bf16.
// ---------------------------------------------------------------------------
__global__ __launch_bounds__(256)
void cc_gemm_m1m(const float* __restrict__ x, const int* __restrict__ pi,
                 const int* __restrict__ pj, const unsigned short* __restrict__ Bt,
                 const float* __restrict__ bias, unsigned short* __restrict__ C) {
  __shared__ unsigned short Asm[128][40];
  __shared__ unsigned short Bsm[128][40];
  int tid = threadIdx.x;
  int lane = tid & 63, wave = tid >> 6;
  int wm = wave >> 1, wn = wave & 1;
  int m0 = blockIdx.y * 128, n0 = blockIdx.x * 128;
  int lr = lane & 15, lk = lane >> 4;
  f32x4 acc[4][4] = {};
  const int r = tid >> 1, kh = tid & 1;
  const int mg = m0 + r;
  const int bb = mg >> 7;
  const int ti_ = pi[mg], tj_ = pj[mg];
  for (int k0 = 0; k0 < 2 * DIM; k0 += 32) {
    {
      int kk = k0 + kh * 16;
      int tok = (kk < DIM) ? ti_ : tj_;
      int kc = (kk < DIM) ? kk : kk - DIM;
      const float* src = x + ((size_t)bb * SEQ + tok) * DIM + kc;
      float4 f0 = *(const float4*)(src);
      float4 f1 = *(const float4*)(src + 4);
      float4 f2 = *(const float4*)(src + 8);
      float4 f3 = *(const float4*)(src + 12);
      unsigned short bvals[16];
      bvals[0] = f2bf(f0.x); bvals[1] = f2bf(f0.y); bvals[2] = f2bf(f0.z); bvals[3] = f2bf(f0.w);
      bvals[4] = f2bf(f1.x); bvals[5] = f2bf(f1.y); bvals[6] = f2bf(f1.z); bvals[7] = f2bf(f1.w);
      bvals[8] = f2bf(f2.x); bvals[9] = f2bf(f2.y); bvals[10] = f2bf(f2.z); bvals[11] = f2bf(f2.w);
      bvals[12] = f2bf(f3.x); bvals[13] = f2bf(f3.y); bvals[14] = f2bf(f3.z); bvals[15] = f2bf(f3.w);
      *(bf16x8*)&Asm[r][kh * 16 + 0] = *(const bf16x8*)&bvals[0];
      *(bf16x8*)&Asm[r][kh * 16 + 8] = *(const bf16x8*)&bvals[8];
      const unsigned short* bsrc = Bt + (size_t)(n0 + r) * (2 * DIM) + k0 + kh * 16;
      *(uint4*)&Bsm[r][kh * 16 + 0] = *(const uint4*)(bsrc);
      *(uint4*)&Bsm[r][kh * 16 + 8] = *(const uint4*)(bsrc + 8);
    }
    __syncthreads();
    bf16x8 af[4], bfr[4];
#pragma unroll
    for (int fm = 0; fm < 4; ++fm)
      af[fm] = *(const bf16x8*)&Asm[wm * 64 + fm * 16 + lr][lk * 8];
#pragma unroll
    for (int fn = 0; fn < 4; ++fn)
      bfr[fn] = *(const bf16x8*)&Bsm[wn * 64 + fn * 16 + lr][lk * 8];
#pragma unroll
    for (int fm = 0; fm < 4; ++fm)
#pragma unroll
      for (int fn = 0; fn < 4; ++fn)
        acc[fm][fn] = __builtin_amdgcn_mfma_f32_16x16x32_bf16(
            af[fm], bfr[fn], acc[fm][fn], 0, 0, 0);
    __syncthreads();
  }
#pragma unroll
  for (int fm = 0; fm < 4; ++fm)
#pragma unroll
    for (int fn = 0; fn < 4; ++fn)
#pragma unroll
      for (int v = 0; v < 4; ++v) {
        int m = m0 + wm * 64 + fm * 16 + lk * 4 + v;
        int n = n0 + wn * 64 + fn * 16 + lr;
        float val = acc[fm][fn][v] + bias[n];
        float g = 0.5f * val * (1.0f + erff(val * 0.70710678f));
        C[(size_t)m * DIM + n] = f2bf(g);
      }
}

// ---------------------------------------------------------------------------
// merged = m1(bf16) @ mrg_w2 + b2 via bf16 MFMA, scattered into out [0,128).
// ---------------------------------------------------------------------------
__global__ __launch_bounds__(256)
void cc_gemm_m2m(const unsigned short* __restrict__ A,
                 const unsigned short* __restrict__ Bt,
                 const float* __restrict__ bias, float* __restrict__ out) {
  __shared__ unsigned short Asm[128][40];
  __shared__ unsigned short Bsm[128][40];
  int tid = threadIdx.x;
  int lane = tid & 63, wave = tid >> 6;
  int wm = wave >> 1, wn = wave & 1;
  int m0 = blockIdx.y * 128, n0 = blockIdx.x * 128;
  int lr = lane & 15, lk = lane >> 4;
  f32x4 acc[4][4] = {};
  const int r = tid >> 1, kh = tid & 1;
  for (int k0 = 0; k0 < DIM; k0 += 32) {
    {
      const unsigned short* src = A + (size_t)(m0 + r) * DIM + k0 + kh * 16;
      *(uint4*)&Asm[r][kh * 16 + 0] = *(const uint4*)(src);
      *(uint4*)&Asm[r][kh * 16 + 8] = *(const uint4*)(src + 8);
      const unsigned short* bsrc = Bt + (size_t)(n0 + r) * DIM + k0 + kh * 16;
      *(uint4*)&Bsm[r][kh * 16 + 0] = *(const uint4*)(bsrc);
      *(uint4*)&Bsm[r][kh * 16 + 8] = *(const uint4*)(bsrc + 8);
    }
    __syncthreads();
    bf16x8 af[4], bfr[4];
#pragma unroll
    for (int fm = 0; fm < 4; ++fm)
      af[fm] = *(const bf16x8*)&Asm[wm * 64 + fm * 16 + lr][lk * 8];
#pragma unroll
    for (int fn = 0; fn < 4; ++fn)
      bfr[fn] = *(const bf16x8*)&Bsm[wn * 64 + fn * 16 + lr][lk * 8];
#pragma unroll
    for (int fm = 0; fm < 4; ++fm)
#pragma unroll
      for (int fn = 0; fn < 4; ++fn)
        acc[fm][fn] = __builtin_amdgcn_mfma_f32_16x16x32_bf16(
            af[fm], bfr[fn], acc[fm][fn], 0, 0, 0);
    __syncthreads();
  }
#pragma unroll
  for (int fm = 0; fm < 4; ++fm)
#pragma unroll
    for (int fn = 0; fn < 4; ++fn)
#pragma unroll
      for (int v = 0; v < 4; ++v) {
        int m = m0 + wm * 64 + fm * 16 + lk * 4 + v;
        int n = n0 + wn * 64 + fn * 16 + lr;
        int bb = m >> 7, p = m & 127;
        float val = acc[fm][fn][v] + bias[n];
        out[((size_t)bb * TLEN + p) * DIM + n] = val;
      }
}

extern "C" void kernel_launch(void* const* d_in, const int* in_sizes, int n_in,
                              void* d_out, int out_size, void* d_ws, size_t ws_size,
                              hipStream_t stream) {
  const float* x      = (const float*)d_in[0];
  const float* imp_w1 = (const float*)d_in[1];
  const float* imp_b1 = (const float*)d_in[2];
  const float* imp_w2 = (const float*)d_in[3];
  const float* imp_b2 = (const float*)d_in[4];
  const float* mrg_w1 = (const float*)d_in[5];
  const float* mrg_b1 = (const float*)d_in[6];
  const float* mrg_w2 = (const float*)d_in[7];
  const float* mrg_b2 = (const float*)d_in[8];
  float* out = (float*)d_out;

  // score (16 MB f32) lives in d_out — fully consumed before output writes.
  float* score = (float*)d_out;

  // workspace: hbuf [0,32MB) during h phase; after imp2 reused for w1t/w2t.
  char* ws = (char*)d_ws;
  float* hbuf  = (float*)ws;                               // 32 MB (h phase)
  unsigned short* w1t = (unsigned short*)ws;               // 16 MB (post-h)
  unsigned short* w2t = (unsigned short*)(ws + ((size_t)16 << 20)); // 8 MB
  unsigned short* m1buf = (unsigned short*)(ws + ((size_t)32 << 20)); // 8 MB bf16
  char* sm = ws + ((size_t)48 << 20);
  float* imp = (float*)sm;              sm += (size_t)BATCH * SEQ * 4;
  float* wv  = (float*)sm;              sm += (size_t)BATCH * SEQ * 4;
  float* rn  = (float*)sm;              sm += (size_t)BATCH * SEQ * 4;
  int* pi    = (int*)sm;                sm += (size_t)BATCH * NPAIRS * 4;
  int* pj    = (int*)sm;                sm += (size_t)BATCH * NPAIRS * 4;
  unsigned char* avail = (unsigned char*)sm; sm += (size_t)BATCH * SEQ;
  int* un    = (int*)sm;                sm += (size_t)BATCH * NUN * 4;
  int* lflag = (int*)sm;                sm += 256;

  cc_probe_f64<<<1, 64, 0, stream>>>(lflag);
  cc_rownorm<<<BATCH * SEQ, 256, 0, stream>>>(x, rn);
  cc_gemm_h<<<dim3(HID / 64, BATCH * SEQ / 64), 256, 0, stream>>>(
      x, imp_w1, imp_b1, hbuf, lflag);
  cc_imp2<<<BATCH * SEQ, 256, 0, stream>>>(hbuf, imp_w2, imp_b2, imp);
  cc_minmax<<<BATCH, 512, 0, stream>>>(imp, wv);
  cc_gemm_score<<<dim3(SEQ / 64, SEQ / 64, BATCH), 256, 0, stream>>>(
      x, rn, wv, score, lflag);
  cc_greedy<<<BATCH, 64, 0, stream>>>(score, pi, pj, avail);
  cc_unmerged<<<BATCH, SEQ, 0, stream>>>(avail, un);
  // hbuf dead; build bf16 transposed weights for the MFMA mergers.
  cc_transpose_bf16<<<dim3(DIM / 32, (2 * DIM) / 32), 256, 0, stream>>>(
      mrg_w1, w1t, 2 * DIM, DIM);
  cc_transpose_bf16<<<dim3(DIM / 32, DIM / 32), 256, 0, stream>>>(
      mrg_w2, w2t, DIM, DIM);
  // score (in d_out) dead from here; start writing outputs.
  cc_unmerged_copy<<<BATCH * NUN, 256, 0, stream>>>(x, un, out);
  cc_gemm_m1m<<<dim3(DIM / 128, BATCH * NPAIRS / 128), 256, 0, stream>>>(
      x, pi, pj, w1t, mrg_b1, m1buf);
  cc_gemm_m2m<<<dim3(DIM / 128, BATCH * NPAIRS / 128), 256, 0, stream>>>(
      m1buf, w2t, mrg_b2, out);
}